// Round 2
// baseline (9335.596 us; speedup 1.0000x reference)
//
#include <hip/hip_runtime.h>

#define K_CODES 8192
#define D_DIM   512
#define N_ROWS  16384
#define TN 64
#define TK 64
#define TD 64
#define SPLITK 4
#define KSPLIT (K_CODES / SPLITK)  /* 2048 */
#define CAND_CAP 32
#define T_MARGIN 1.3e-4   /* > ULP(650)=6.1e-5 + 4*einsum-noise; provably covers ref winner */

// ---------------------------------------------------------------------------
// K1: fp64 GEMM, per-(row,split) MAX of dot (v = -2*dot minimized <=> dot max)
// ---------------------------------------------------------------------------
__global__ __launch_bounds__(256, 2)
void vq_min_kernel(const float* __restrict__ x,
                   const float* __restrict__ cb,
                   double* __restrict__ best_v) {
    __shared__ double As[TD][TN];   // [d][n] 32 KB
    __shared__ double Bs[TD][TK];   // [d][k] 32 KB

    const int t  = threadIdx.x;
    const int tx = t & 15;
    const int ty = t >> 4;
    const int sr = t & 63;
    const int sg = t >> 6;
    const int row0 = blockIdx.x * TN;
    const int k0   = blockIdx.y * KSPLIT;

    double bdot[4];
#pragma unroll
    for (int i = 0; i < 4; ++i) bdot[i] = -1.0e300;

    for (int kt = 0; kt < KSPLIT / TK; ++kt) {
        double acc[4][4];
#pragma unroll
        for (int i = 0; i < 4; ++i)
#pragma unroll
            for (int j = 0; j < 4; ++j) acc[i][j] = 0.0;

        for (int dc = 0; dc < D_DIM / TD; ++dc) {
            __syncthreads();
            {
                const float* ap = x  + (size_t)(row0 + sr) * D_DIM + dc * TD + sg * 16;
                const float* bp = cb + (size_t)(k0 + kt * TK + sr) * D_DIM + dc * TD + sg * 16;
                float4 a0 = ((const float4*)ap)[0];
                float4 a1 = ((const float4*)ap)[1];
                float4 a2 = ((const float4*)ap)[2];
                float4 a3 = ((const float4*)ap)[3];
                float4 b0 = ((const float4*)bp)[0];
                float4 b1 = ((const float4*)bp)[1];
                float4 b2 = ((const float4*)bp)[2];
                float4 b3 = ((const float4*)bp)[3];
                const int db = sg * 16;
                As[db +  0][sr] = a0.x; As[db +  1][sr] = a0.y;
                As[db +  2][sr] = a0.z; As[db +  3][sr] = a0.w;
                As[db +  4][sr] = a1.x; As[db +  5][sr] = a1.y;
                As[db +  6][sr] = a1.z; As[db +  7][sr] = a1.w;
                As[db +  8][sr] = a2.x; As[db +  9][sr] = a2.y;
                As[db + 10][sr] = a2.z; As[db + 11][sr] = a2.w;
                As[db + 12][sr] = a3.x; As[db + 13][sr] = a3.y;
                As[db + 14][sr] = a3.z; As[db + 15][sr] = a3.w;
                Bs[db +  0][sr] = b0.x; Bs[db +  1][sr] = b0.y;
                Bs[db +  2][sr] = b0.z; Bs[db +  3][sr] = b0.w;
                Bs[db +  4][sr] = b1.x; Bs[db +  5][sr] = b1.y;
                Bs[db +  6][sr] = b1.z; Bs[db +  7][sr] = b1.w;
                Bs[db +  8][sr] = b2.x; Bs[db +  9][sr] = b2.y;
                Bs[db + 10][sr] = b2.z; Bs[db + 11][sr] = b2.w;
                Bs[db + 12][sr] = b3.x; Bs[db + 13][sr] = b3.y;
                Bs[db + 14][sr] = b3.z; Bs[db + 15][sr] = b3.w;
            }
            __syncthreads();
#pragma unroll 8
            for (int d = 0; d < TD; ++d) {
                double av[4], bv[4];
#pragma unroll
                for (int i = 0; i < 4; ++i) av[i] = As[d][ty + 16 * i];
#pragma unroll
                for (int j = 0; j < 4; ++j) bv[j] = Bs[d][tx + 16 * j];
#pragma unroll
                for (int i = 0; i < 4; ++i)
#pragma unroll
                    for (int j = 0; j < 4; ++j)
                        acc[i][j] = fma(av[i], bv[j], acc[i][j]);
            }
        }
#pragma unroll
        for (int i = 0; i < 4; ++i)
#pragma unroll
            for (int j = 0; j < 4; ++j)
                if (acc[i][j] > bdot[i]) bdot[i] = acc[i][j];
    }

    __syncthreads();
    double* rs = &As[0][0];          // 64 rows x 16 slices
#pragma unroll
    for (int i = 0; i < 4; ++i) rs[(ty + 16 * i) * 16 + tx] = bdot[i];
    __syncthreads();
    if (t < TN) {
        double bd = rs[t * 16];
#pragma unroll
        for (int u = 1; u < 16; ++u) {
            double s = rs[t * 16 + u];
            if (s > bd) bd = s;
        }
        // v = -2*dot ; store the minimum v for this split
        best_v[(size_t)(row0 + t) * SPLITK + blockIdx.y] = -2.0 * bd;
    }
}

// ---------------------------------------------------------------------------
// K2: merge splits -> vmin[row]; zero candidate counters; zero loss acc.
// ---------------------------------------------------------------------------
__global__ void vq_vmin_kernel(const double* __restrict__ best_v,
                               double* __restrict__ vmin,
                               int* __restrict__ cnt,
                               double* __restrict__ loss_acc) {
    const int row = blockIdx.x * blockDim.x + threadIdx.x;
    if (row >= N_ROWS) return;
    if (row == 0) *loss_acc = 0.0;
    double v = best_v[(size_t)row * SPLITK];
#pragma unroll
    for (int sp = 1; sp < SPLITK; ++sp) {
        double s = best_v[(size_t)row * SPLITK + sp];
        if (s < v) v = s;
    }
    vmin[row] = v;
    cnt[row] = 0;
}

// ---------------------------------------------------------------------------
// K3: second fp64 GEMM pass; collect all k with v <= vmin + T into cand list.
// ---------------------------------------------------------------------------
__global__ __launch_bounds__(256, 2)
void vq_collect_kernel(const float* __restrict__ x,
                       const float* __restrict__ cb,
                       const double* __restrict__ vmin,
                       int* __restrict__ cnt,
                       int* __restrict__ cand) {
    __shared__ double As[TD][TN];
    __shared__ double Bs[TD][TK];

    const int t  = threadIdx.x;
    const int tx = t & 15;
    const int ty = t >> 4;
    const int sr = t & 63;
    const int sg = t >> 6;
    const int row0 = blockIdx.x * TN;
    const int k0   = blockIdx.y * KSPLIT;

    double vlim[4];
#pragma unroll
    for (int i = 0; i < 4; ++i) vlim[i] = vmin[row0 + ty + 16 * i] + T_MARGIN;

    for (int kt = 0; kt < KSPLIT / TK; ++kt) {
        double acc[4][4];
#pragma unroll
        for (int i = 0; i < 4; ++i)
#pragma unroll
            for (int j = 0; j < 4; ++j) acc[i][j] = 0.0;

        for (int dc = 0; dc < D_DIM / TD; ++dc) {
            __syncthreads();
            {
                const float* ap = x  + (size_t)(row0 + sr) * D_DIM + dc * TD + sg * 16;
                const float* bp = cb + (size_t)(k0 + kt * TK + sr) * D_DIM + dc * TD + sg * 16;
                float4 a0 = ((const float4*)ap)[0];
                float4 a1 = ((const float4*)ap)[1];
                float4 a2 = ((const float4*)ap)[2];
                float4 a3 = ((const float4*)ap)[3];
                float4 b0 = ((const float4*)bp)[0];
                float4 b1 = ((const float4*)bp)[1];
                float4 b2 = ((const float4*)bp)[2];
                float4 b3 = ((const float4*)bp)[3];
                const int db = sg * 16;
                As[db +  0][sr] = a0.x; As[db +  1][sr] = a0.y;
                As[db +  2][sr] = a0.z; As[db +  3][sr] = a0.w;
                As[db +  4][sr] = a1.x; As[db +  5][sr] = a1.y;
                As[db +  6][sr] = a1.z; As[db +  7][sr] = a1.w;
                As[db +  8][sr] = a2.x; As[db +  9][sr] = a2.y;
                As[db + 10][sr] = a2.z; As[db + 11][sr] = a2.w;
                As[db + 12][sr] = a3.x; As[db + 13][sr] = a3.y;
                As[db + 14][sr] = a3.z; As[db + 15][sr] = a3.w;
                Bs[db +  0][sr] = b0.x; Bs[db +  1][sr] = b0.y;
                Bs[db +  2][sr] = b0.z; Bs[db +  3][sr] = b0.w;
                Bs[db +  4][sr] = b1.x; Bs[db +  5][sr] = b1.y;
                Bs[db +  6][sr] = b1.z; Bs[db +  7][sr] = b1.w;
                Bs[db +  8][sr] = b2.x; Bs[db +  9][sr] = b2.y;
                Bs[db + 10][sr] = b2.z; Bs[db + 11][sr] = b2.w;
                Bs[db + 12][sr] = b3.x; Bs[db + 13][sr] = b3.y;
                Bs[db + 14][sr] = b3.z; Bs[db + 15][sr] = b3.w;
            }
            __syncthreads();
#pragma unroll 8
            for (int d = 0; d < TD; ++d) {
                double av[4], bv[4];
#pragma unroll
                for (int i = 0; i < 4; ++i) av[i] = As[d][ty + 16 * i];
#pragma unroll
                for (int j = 0; j < 4; ++j) bv[j] = Bs[d][tx + 16 * j];
#pragma unroll
                for (int i = 0; i < 4; ++i)
#pragma unroll
                    for (int j = 0; j < 4; ++j)
                        acc[i][j] = fma(av[i], bv[j], acc[i][j]);
            }
        }
#pragma unroll
        for (int i = 0; i < 4; ++i) {
            const int row = row0 + ty + 16 * i;
#pragma unroll
            for (int j = 0; j < 4; ++j) {
                const double v = -2.0 * acc[i][j];
                if (v <= vlim[i]) {
                    const int k = k0 + kt * TK + tx + 16 * j;
                    int pos = atomicAdd(&cnt[row], 1);
                    if (pos < CAND_CAP) cand[(size_t)row * CAND_CAP + pos] = k;
                }
            }
        }
        __syncthreads();
    }
}

// ---------------------------------------------------------------------------
// K4: bit-exact numpy (fp32, baseline-SSE3) replay on the shortlist.
//   s_n: np pairwise sum of fp32(z*z) (8-accumulator blocks of 128)
//   dot: einsum sum_of_products_contig_contig_outstride0_two, vstep=4, no FMA,
//        4x-unrolled chain order (groups 12,8,4,0 within each 16-block),
//        SSE3 hadd horizontal sum (S0+S1)+(S2+S3)
//   dist = fp32(s_n - 2*dot)   (the +||c||^2 term is absorbed by rounding)
// ---------------------------------------------------------------------------
__device__ __forceinline__ float np_pair128_sq(const float* __restrict__ a) {
    float r[8];
#pragma unroll
    for (int j = 0; j < 8; ++j) r[j] = __fmul_rn(a[j], a[j]);
    for (int i = 8; i < 128; i += 8)
#pragma unroll
        for (int j = 0; j < 8; ++j) r[j] = __fadd_rn(r[j], __fmul_rn(a[i + j], a[i + j]));
    return __fadd_rn(__fadd_rn(__fadd_rn(r[0], r[1]), __fadd_rn(r[2], r[3])),
                     __fadd_rn(__fadd_rn(r[4], r[5]), __fadd_rn(r[6], r[7])));
}

__device__ __forceinline__ float np_einsum_dot(const float* __restrict__ a,
                                               const float* __restrict__ b) {
    float S0 = 0.f, S1 = 0.f, S2 = 0.f, S3 = 0.f;
    for (int i = 0; i < D_DIM; i += 16) {
        // numpy chains ab3 (offset 12) first, then 8, 4, 0
        S0 = __fadd_rn(S0, __fmul_rn(a[i + 12], b[i + 12]));
        S1 = __fadd_rn(S1, __fmul_rn(a[i + 13], b[i + 13]));
        S2 = __fadd_rn(S2, __fmul_rn(a[i + 14], b[i + 14]));
        S3 = __fadd_rn(S3, __fmul_rn(a[i + 15], b[i + 15]));
        S0 = __fadd_rn(S0, __fmul_rn(a[i +  8], b[i +  8]));
        S1 = __fadd_rn(S1, __fmul_rn(a[i +  9], b[i +  9]));
        S2 = __fadd_rn(S2, __fmul_rn(a[i + 10], b[i + 10]));
        S3 = __fadd_rn(S3, __fmul_rn(a[i + 11], b[i + 11]));
        S0 = __fadd_rn(S0, __fmul_rn(a[i +  4], b[i +  4]));
        S1 = __fadd_rn(S1, __fmul_rn(a[i +  5], b[i +  5]));
        S2 = __fadd_rn(S2, __fmul_rn(a[i +  6], b[i +  6]));
        S3 = __fadd_rn(S3, __fmul_rn(a[i +  7], b[i +  7]));
        S0 = __fadd_rn(S0, __fmul_rn(a[i +  0], b[i +  0]));
        S1 = __fadd_rn(S1, __fmul_rn(a[i +  1], b[i +  1]));
        S2 = __fadd_rn(S2, __fmul_rn(a[i +  2], b[i +  2]));
        S3 = __fadd_rn(S3, __fmul_rn(a[i +  3], b[i +  3]));
    }
    return __fadd_rn(__fadd_rn(S0, S1), __fadd_rn(S2, S3));
}

__global__ void vq_decide_kernel(const float* __restrict__ x,
                                 const float* __restrict__ cb,
                                 const int* __restrict__ cnt,
                                 const int* __restrict__ cand,
                                 int* __restrict__ idx_i,
                                 float* __restrict__ idx_f) {
    const int row = blockIdx.x * blockDim.x + threadIdx.x;
    if (row >= N_ROWS) return;
    int c = cnt[row];
    if (c > CAND_CAP) c = CAND_CAP;
    int win;
    if (c == 1) {
        win = cand[(size_t)row * CAND_CAP];
    } else {
        const float* zr = x + (size_t)row * D_DIM;
        const float s32 = __fadd_rn(__fadd_rn(np_pair128_sq(zr),       np_pair128_sq(zr + 128)),
                                    __fadd_rn(np_pair128_sq(zr + 256), np_pair128_sq(zr + 384)));
        float bd = 0.f;
        win = -1;
        for (int u = 0; u < c; ++u) {
            const int k = cand[(size_t)row * CAND_CAP + u];
            const float e = np_einsum_dot(zr, cb + (size_t)k * D_DIM);
            const float dist = __fadd_rn(s32, __fmul_rn(-2.0f, e));
            if (win < 0 || dist < bd || (dist == bd && k < win)) { bd = dist; win = k; }
        }
    }
    idx_i[row] = win;
    idx_f[row] = (float)win;
}

// ---------------------------------------------------------------------------
// K5: gather z_q with exact fp32 straight-through arithmetic + fused loss.
// ---------------------------------------------------------------------------
__global__ void vq_gather_kernel(const float* __restrict__ x,
                                 const float* __restrict__ cb,
                                 const int* __restrict__ idx,
                                 float* __restrict__ zq_out,
                                 double* __restrict__ loss_acc) {
    const int row = blockIdx.x;
    const int t   = threadIdx.x;   // 128
    const int k   = idx[row];
    const float4 c  = ((const float4*)(cb + (size_t)k   * D_DIM))[t];
    const float4 xv = ((const float4*)(x  + (size_t)row * D_DIM))[t];
    float4 o;
    o.x = __fadd_rn(xv.x, __fsub_rn(c.x, xv.x));
    o.y = __fadd_rn(xv.y, __fsub_rn(c.y, xv.y));
    o.z = __fadd_rn(xv.z, __fsub_rn(c.z, xv.z));
    o.w = __fadd_rn(xv.w, __fsub_rn(c.w, xv.w));
    ((float4*)(zq_out + (size_t)row * D_DIM))[t] = o;
    const double d0 = (double)c.x - (double)xv.x;
    const double d1 = (double)c.y - (double)xv.y;
    const double d2 = (double)c.z - (double)xv.z;
    const double d3 = (double)c.w - (double)xv.w;
    double s = d0 * d0 + d1 * d1 + d2 * d2 + d3 * d3;
#pragma unroll
    for (int off = 32; off > 0; off >>= 1) s += __shfl_xor(s, off, 64);
    __shared__ double red[2];
    if ((t & 63) == 0) red[t >> 6] = s;
    __syncthreads();
    if (t == 0) atomicAdd(loss_acc, red[0] + red[1]);
}

__global__ void vq_finalize_kernel(const double* __restrict__ loss_acc,
                                   float* __restrict__ losses) {
    const float l = (float)(*loss_acc / (double)((size_t)N_ROWS * D_DIM));
    losses[0] = l;
    losses[1] = l;
}

extern "C" void kernel_launch(void* const* d_in, const int* in_sizes, int n_in,
                              void* d_out, int out_size, void* d_ws, size_t ws_size,
                              hipStream_t stream) {
    const float* x  = (const float*)d_in[0];   // [16384, 512]
    const float* cb = (const float*)d_in[1];   // [8192, 512]
    float* out    = (float*)d_out;
    float* zq     = out;
    float* losses = out + (size_t)N_ROWS * D_DIM;
    float* idx_f  = losses + 2;

    char* ws = (char*)d_ws;
    double* best_v   = (double*)(ws);                         // 512 KB
    double* vmin     = (double*)(ws + (512 << 10));           // 128 KB
    int*    cnt      = (int*)   (ws + (640 << 10));           // 64 KB
    int*    cand     = (int*)   (ws + (704 << 10));           // 2 MB
    double* loss_acc = (double*)(ws + (2752 << 10));          // 8 B
    int*    idx_i    = (int*)   (ws + (2753 << 10));          // 64 KB

    hipLaunchKernelGGL(vq_min_kernel, dim3(N_ROWS / TN, SPLITK), dim3(256), 0, stream,
                       x, cb, best_v);
    hipLaunchKernelGGL(vq_vmin_kernel, dim3(N_ROWS / 256), dim3(256), 0, stream,
                       best_v, vmin, cnt, loss_acc);
    hipLaunchKernelGGL(vq_collect_kernel, dim3(N_ROWS / TN, SPLITK), dim3(256), 0, stream,
                       x, cb, vmin, cnt, cand);
    hipLaunchKernelGGL(vq_decide_kernel, dim3(N_ROWS / 256), dim3(256), 0, stream,
                       x, cb, cnt, cand, idx_i, idx_f);
    hipLaunchKernelGGL(vq_gather_kernel, dim3(N_ROWS), dim3(128), 0, stream,
                       x, cb, idx_i, zq, loss_acc);
    hipLaunchKernelGGL(vq_finalize_kernel, dim3(1), dim3(1), 0, stream,
                       loss_acc, losses);
}

// Round 4
// 998.193 us; speedup vs baseline: 9.3525x; 9.3525x over previous
//
#include <hip/hip_runtime.h>

#define K_CODES 8192
#define D_DIM   512
#define N_ROWS  16384
#define NSPLIT  32          /* code splits of 256 */
#define CAP     8
#define T2      1.0e-4f     /* dot-space margin: need 3.1e-5 (ULP/2 in dot space) + eps */

typedef __attribute__((ext_vector_type(8))) short bf16x8;
typedef __attribute__((ext_vector_type(4))) float f32x4;
typedef unsigned char uchar;

// order-preserving float<->uint key (for unsigned atomicMax)
__device__ __forceinline__ unsigned fkey(float f) {
    unsigned b = __float_as_uint(f);
    return (b & 0x80000000u) ? ~b : (b | 0x80000000u);
}
__device__ __forceinline__ float finv(unsigned k) {
    return __uint_as_float((k & 0x80000000u) ? (k & 0x7fffffffu) : ~k);
}

// split two floats into packed bf16 hi (x ~= hi + lo) pairs
__device__ __forceinline__ void split2(float x0, float x1, unsigned& h, unsigned& l) {
    unsigned u0 = __float_as_uint(x0), u1 = __float_as_uint(x1);
    unsigned h0 = (u0 + 0x8000u) & 0xffff0000u;
    unsigned h1 = (u1 + 0x8000u) & 0xffff0000u;
    float l0 = x0 - __uint_as_float(h0);
    float l1 = x1 - __uint_as_float(h1);
    h = (h0 >> 16) | (h1 & 0xffff0000u);
    l = ((__float_as_uint(l0) + 0x8000u) >> 16) |
        ((__float_as_uint(l1) + 0x8000u) & 0xffff0000u);
}

// ---------------------------------------------------------------------------
// K1: screening. Block = 128 rows x 256 codes. bf16 split MFMA (hh+hl+lh),
// dot error ~1e-8. Outputs per (row, split): screen max dot, push count,
// up to CAP candidate in-split byte offsets.
// ---------------------------------------------------------------------------
__global__ __launch_bounds__(256, 2)
void vq_screen(const float* __restrict__ x, const float* __restrict__ cb,
               float* __restrict__ g_dmax, uchar* __restrict__ g_cnt,
               uchar* __restrict__ g_cand) {
    __shared__ unsigned short Ah[128][40], Al[128][40];
    __shared__ unsigned short Bh[128][40], Bl[128][40];
    __shared__ unsigned vkey[128];
    __shared__ int ccnt[128];
    __shared__ uchar clist[128][CAP];

    const int t    = threadIdx.x;
    const int w    = t >> 6, lane = t & 63;
    const int wr   = (w & 1) * 64;
    const int wc   = (w >> 1) * 64;
    const int fr   = lane & 15;
    const int quad = lane >> 4;
    const int kq   = quad * 8;
    const int row0  = blockIdx.y * 128;
    const int kbase = blockIdx.x * 256;
    const int srow = t >> 1;
    const int scol = (t & 1) * 16;

    if (t < 128) { vkey[t] = 0u; ccnt[t] = 0; }

    for (int kt = 0; kt < 2; ++kt) {
        f32x4 acc[4][4];
#pragma unroll
        for (int i = 0; i < 4; ++i)
#pragma unroll
            for (int j = 0; j < 4; ++j) acc[i][j] = (f32x4)0.0f;

        for (int dc = 0; dc < D_DIM / 32; ++dc) {
            __syncthreads();
            {
                const float* ap = x  + (size_t)(row0 + srow) * D_DIM + dc * 32 + scol;
                const float* bp = cb + (size_t)(kbase + kt * 128 + srow) * D_DIM + dc * 32 + scol;
                float va[16], vb[16];
#pragma unroll
                for (int q = 0; q < 4; ++q) {
                    *(float4*)&va[4 * q] = ((const float4*)ap)[q];
                    *(float4*)&vb[4 * q] = ((const float4*)bp)[q];
                }
                unsigned ha[8], la[8], hb[8], lb[8];
#pragma unroll
                for (int e = 0; e < 8; ++e) {
                    split2(va[2 * e], va[2 * e + 1], ha[e], la[e]);
                    split2(vb[2 * e], vb[2 * e + 1], hb[e], lb[e]);
                }
                *(uint4*)&Ah[srow][scol]     = make_uint4(ha[0], ha[1], ha[2], ha[3]);
                *(uint4*)&Ah[srow][scol + 8] = make_uint4(ha[4], ha[5], ha[6], ha[7]);
                *(uint4*)&Al[srow][scol]     = make_uint4(la[0], la[1], la[2], la[3]);
                *(uint4*)&Al[srow][scol + 8] = make_uint4(la[4], la[5], la[6], la[7]);
                *(uint4*)&Bh[srow][scol]     = make_uint4(hb[0], hb[1], hb[2], hb[3]);
                *(uint4*)&Bh[srow][scol + 8] = make_uint4(hb[4], hb[5], hb[6], hb[7]);
                *(uint4*)&Bl[srow][scol]     = make_uint4(lb[0], lb[1], lb[2], lb[3]);
                *(uint4*)&Bl[srow][scol + 8] = make_uint4(lb[4], lb[5], lb[6], lb[7]);
            }
            __syncthreads();
            bf16x8 ahf[4], alf[4], bhf[4], blf[4];
#pragma unroll
            for (int i = 0; i < 4; ++i) {
                ahf[i] = *(const bf16x8*)&Ah[wr + i * 16 + fr][kq];
                alf[i] = *(const bf16x8*)&Al[wr + i * 16 + fr][kq];
                bhf[i] = *(const bf16x8*)&Bh[wc + i * 16 + fr][kq];
                blf[i] = *(const bf16x8*)&Bl[wc + i * 16 + fr][kq];
            }
#pragma unroll
            for (int i = 0; i < 4; ++i)
#pragma unroll
                for (int j = 0; j < 4; ++j) {
                    acc[i][j] = __builtin_amdgcn_mfma_f32_16x16x32_bf16(alf[i], bhf[j], acc[i][j], 0, 0, 0);
                    acc[i][j] = __builtin_amdgcn_mfma_f32_16x16x32_bf16(ahf[i], blf[j], acc[i][j], 0, 0, 0);
                    acc[i][j] = __builtin_amdgcn_mfma_f32_16x16x32_bf16(ahf[i], bhf[j], acc[i][j], 0, 0, 0);
                }
        }

        __syncthreads();
#pragma unroll
        for (int i = 0; i < 4; ++i)
#pragma unroll
            for (int r = 0; r < 4; ++r) {
                float m = fmaxf(fmaxf(acc[i][0][r], acc[i][1][r]),
                                fmaxf(acc[i][2][r], acc[i][3][r]));
                m = fmaxf(m, __shfl_xor(m, 1));
                m = fmaxf(m, __shfl_xor(m, 2));
                m = fmaxf(m, __shfl_xor(m, 4));
                m = fmaxf(m, __shfl_xor(m, 8));
                if (fr == 0)
                    atomicMax(&vkey[wr + i * 16 + quad * 4 + r], fkey(m));
            }
        __syncthreads();
#pragma unroll
        for (int i = 0; i < 4; ++i)
#pragma unroll
            for (int r = 0; r < 4; ++r) {
                const int row = wr + i * 16 + quad * 4 + r;
                const float thr = finv(vkey[row]) - T2;
#pragma unroll
                for (int j = 0; j < 4; ++j) {
                    if (acc[i][j][r] >= thr) {
                        int p = atomicAdd(&ccnt[row], 1);
                        if (p < CAP)
                            clist[row][p] = (uchar)(kt * 128 + wc + j * 16 + fr);
                    }
                }
            }
    }

    __syncthreads();
    if (t < 128) {
        const size_t o = (size_t)(row0 + t) * NSPLIT + blockIdx.x;
        g_dmax[o] = finv(vkey[t]);
        int c = ccnt[t];
        g_cnt[o] = (uchar)(c > 255 ? 255 : c);
        ((uint2*)g_cand)[o] = *(const uint2*)clist[t];
    }
}

// ---------------------------------------------------------------------------
// bit-exact numpy fp32 (baseline SSE3) replay — validated absmax=0 in round 2
// ---------------------------------------------------------------------------
__device__ __forceinline__ float np_pair128_sq(const float* __restrict__ a) {
    float r[8];
#pragma unroll
    for (int j = 0; j < 8; ++j) r[j] = __fmul_rn(a[j], a[j]);
    for (int i = 8; i < 128; i += 8)
#pragma unroll
        for (int j = 0; j < 8; ++j) r[j] = __fadd_rn(r[j], __fmul_rn(a[i + j], a[i + j]));
    return __fadd_rn(__fadd_rn(__fadd_rn(r[0], r[1]), __fadd_rn(r[2], r[3])),
                     __fadd_rn(__fadd_rn(r[4], r[5]), __fadd_rn(r[6], r[7])));
}

__device__ __forceinline__ float np_einsum_dot(const float* __restrict__ a,
                                               const float* __restrict__ b) {
    float S0 = 0.f, S1 = 0.f, S2 = 0.f, S3 = 0.f;
    for (int i = 0; i < D_DIM; i += 16) {
        S0 = __fadd_rn(S0, __fmul_rn(a[i + 12], b[i + 12]));
        S1 = __fadd_rn(S1, __fmul_rn(a[i + 13], b[i + 13]));
        S2 = __fadd_rn(S2, __fmul_rn(a[i + 14], b[i + 14]));
        S3 = __fadd_rn(S3, __fmul_rn(a[i + 15], b[i + 15]));
        S0 = __fadd_rn(S0, __fmul_rn(a[i +  8], b[i +  8]));
        S1 = __fadd_rn(S1, __fmul_rn(a[i +  9], b[i +  9]));
        S2 = __fadd_rn(S2, __fmul_rn(a[i + 10], b[i + 10]));
        S3 = __fadd_rn(S3, __fmul_rn(a[i + 11], b[i + 11]));
        S0 = __fadd_rn(S0, __fmul_rn(a[i +  4], b[i +  4]));
        S1 = __fadd_rn(S1, __fmul_rn(a[i +  5], b[i +  5]));
        S2 = __fadd_rn(S2, __fmul_rn(a[i +  6], b[i +  6]));
        S3 = __fadd_rn(S3, __fmul_rn(a[i +  7], b[i +  7]));
        S0 = __fadd_rn(S0, __fmul_rn(a[i +  0], b[i +  0]));
        S1 = __fadd_rn(S1, __fmul_rn(a[i +  1], b[i +  1]));
        S2 = __fadd_rn(S2, __fmul_rn(a[i +  2], b[i +  2]));
        S3 = __fadd_rn(S3, __fmul_rn(a[i +  3], b[i +  3]));
    }
    return __fadd_rn(__fadd_rn(S0, S1), __fadd_rn(S2, S3));
}

// ---------------------------------------------------------------------------
// K2: wave-per-row decide. Candidate replay lane-parallel; on per-split cap
// overflow, exact-replays ALL 256 codes of that split (coverage then depends
// only on split maxima, not candidate lists).
// ---------------------------------------------------------------------------
__global__ __launch_bounds__(256)
void vq_decide(const float* __restrict__ x, const float* __restrict__ cb,
               const float* __restrict__ g_dmax, const uchar* __restrict__ g_cnt,
               const uchar* __restrict__ g_cand,
               int* __restrict__ idx_i, float* __restrict__ idx_f,
               double* __restrict__ loss_acc) {
    const int wv = threadIdx.x >> 6, lane = threadIdx.x & 63;
    const int row = blockIdx.x * 4 + wv;
    if (blockIdx.x == 0 && threadIdx.x == 0) *loss_acc = 0.0;
    const float* dm = g_dmax + (size_t)row * NSPLIT;

    float g = dm[lane & 31];
    g = fmaxf(g, __shfl_xor(g, 1));
    g = fmaxf(g, __shfl_xor(g, 2));
    g = fmaxf(g, __shfl_xor(g, 4));
    g = fmaxf(g, __shfl_xor(g, 8));
    g = fmaxf(g, __shfl_xor(g, 16));
    const float thr = g - T2;

    const float* zr = x + (size_t)row * D_DIM;
    const float sn = __fadd_rn(__fadd_rn(np_pair128_sq(zr),       np_pair128_sq(zr + 128)),
                               __fadd_rn(np_pair128_sq(zr + 256), np_pair128_sq(zr + 384)));

    float bd = 3.4e38f;
    int   bk = 0x7fffffff;
    for (int s = 0; s < NSPLIT; ++s) {
        if (dm[s] < thr) continue;
        const size_t o = (size_t)row * NSPLIT + s;
        const int c = g_cnt[o];
        if (c <= CAP) {
            if (lane < c) {
                const int k = s * 256 + g_cand[o * CAP + lane];
                const float e = np_einsum_dot(zr, cb + (size_t)k * D_DIM);
                const float d = __fadd_rn(sn, __fmul_rn(-2.0f, e));
                if (d < bd || (d == bd && k < bk)) { bd = d; bk = k; }
            }
        } else {
            for (int u = 0; u < 4; ++u) {
                const int k = s * 256 + lane * 4 + u;
                const float e = np_einsum_dot(zr, cb + (size_t)k * D_DIM);
                const float d = __fadd_rn(sn, __fmul_rn(-2.0f, e));
                if (d < bd || (d == bd && k < bk)) { bd = d; bk = k; }
            }
        }
    }
#pragma unroll
    for (int off = 1; off < 64; off <<= 1) {
        const float od = __shfl_xor(bd, off);
        const int   ok = __shfl_xor(bk, off);
        if (od < bd || (od == bd && ok < bk)) { bd = od; bk = ok; }
    }
    if (lane == 0) { idx_i[row] = bk; idx_f[row] = (float)bk; }
}

// ---------------------------------------------------------------------------
// K3: gather z_q (exact fp32 straight-through arithmetic) + fused loss.
// ---------------------------------------------------------------------------
__global__ void vq_gather_kernel(const float* __restrict__ x,
                                 const float* __restrict__ cb,
                                 const int* __restrict__ idx,
                                 float* __restrict__ zq_out,
                                 double* __restrict__ loss_acc) {
    const int row = blockIdx.x;
    const int t   = threadIdx.x;   // 128
    const int k   = idx[row];
    const float4 c  = ((const float4*)(cb + (size_t)k   * D_DIM))[t];
    const float4 xv = ((const float4*)(x  + (size_t)row * D_DIM))[t];
    float4 o;
    o.x = __fadd_rn(xv.x, __fsub_rn(c.x, xv.x));
    o.y = __fadd_rn(xv.y, __fsub_rn(c.y, xv.y));
    o.z = __fadd_rn(xv.z, __fsub_rn(c.z, xv.z));
    o.w = __fadd_rn(xv.w, __fsub_rn(c.w, xv.w));
    ((float4*)(zq_out + (size_t)row * D_DIM))[t] = o;
    const double d0 = (double)c.x - (double)xv.x;
    const double d1 = (double)c.y - (double)xv.y;
    const double d2 = (double)c.z - (double)xv.z;
    const double d3 = (double)c.w - (double)xv.w;
    double s = d0 * d0 + d1 * d1 + d2 * d2 + d3 * d3;
#pragma unroll
    for (int off = 32; off > 0; off >>= 1) s += __shfl_xor(s, off, 64);
    __shared__ double red[2];
    if ((t & 63) == 0) red[t >> 6] = s;
    __syncthreads();
    if (t == 0) atomicAdd(loss_acc, red[0] + red[1]);
}

__global__ void vq_finalize_kernel(const double* __restrict__ loss_acc,
                                   float* __restrict__ losses) {
    const float l = (float)(*loss_acc / (double)((size_t)N_ROWS * D_DIM));
    losses[0] = l;
    losses[1] = l;
}

// ===========================================================================
// Fallback path (round-2-proven exact fp64 pipeline) — used if ws too small.
// ===========================================================================
#define FB_TN 64
#define FB_TK 64
#define FB_TD 64
#define FB_SPLITK 4
#define FB_KSPLIT (K_CODES / FB_SPLITK)
#define FB_CAP 32
#define FB_MARGIN 1.3e-4

__global__ __launch_bounds__(256, 2)
void fb_min_kernel(const float* __restrict__ x, const float* __restrict__ cb,
                   double* __restrict__ best_v) {
    __shared__ double As[FB_TD][FB_TN];
    __shared__ double Bs[FB_TD][FB_TK];
    const int t = threadIdx.x, tx = t & 15, ty = t >> 4, sr = t & 63, sg = t >> 6;
    const int row0 = blockIdx.x * FB_TN, k0 = blockIdx.y * FB_KSPLIT;
    double bdot[4];
#pragma unroll
    for (int i = 0; i < 4; ++i) bdot[i] = -1.0e300;
    for (int kt = 0; kt < FB_KSPLIT / FB_TK; ++kt) {
        double acc[4][4];
#pragma unroll
        for (int i = 0; i < 4; ++i)
#pragma unroll
            for (int j = 0; j < 4; ++j) acc[i][j] = 0.0;
        for (int dc = 0; dc < D_DIM / FB_TD; ++dc) {
            __syncthreads();
            const float* ap = x  + (size_t)(row0 + sr) * D_DIM + dc * FB_TD + sg * 16;
            const float* bp = cb + (size_t)(k0 + kt * FB_TK + sr) * D_DIM + dc * FB_TD + sg * 16;
#pragma unroll
            for (int q = 0; q < 4; ++q) {
                float4 a = ((const float4*)ap)[q];
                float4 b = ((const float4*)bp)[q];
                const int db = sg * 16 + q * 4;
                As[db + 0][sr] = a.x; As[db + 1][sr] = a.y; As[db + 2][sr] = a.z; As[db + 3][sr] = a.w;
                Bs[db + 0][sr] = b.x; Bs[db + 1][sr] = b.y; Bs[db + 2][sr] = b.z; Bs[db + 3][sr] = b.w;
            }
            __syncthreads();
#pragma unroll 8
            for (int d = 0; d < FB_TD; ++d) {
                double av[4], bv[4];
#pragma unroll
                for (int i = 0; i < 4; ++i) av[i] = As[d][ty + 16 * i];
#pragma unroll
                for (int j = 0; j < 4; ++j) bv[j] = Bs[d][tx + 16 * j];
#pragma unroll
                for (int i = 0; i < 4; ++i)
#pragma unroll
                    for (int j = 0; j < 4; ++j) acc[i][j] = fma(av[i], bv[j], acc[i][j]);
            }
        }
#pragma unroll
        for (int i = 0; i < 4; ++i)
#pragma unroll
            for (int j = 0; j < 4; ++j)
                if (acc[i][j] > bdot[i]) bdot[i] = acc[i][j];
    }
    __syncthreads();
    double* rs = &As[0][0];
#pragma unroll
    for (int i = 0; i < 4; ++i) rs[(ty + 16 * i) * 16 + tx] = bdot[i];
    __syncthreads();
    if (t < FB_TN) {
        double bd = rs[t * 16];
#pragma unroll
        for (int u = 1; u < 16; ++u) { double s = rs[t * 16 + u]; if (s > bd) bd = s; }
        best_v[(size_t)(row0 + t) * FB_SPLITK + blockIdx.y] = -2.0 * bd;
    }
}

__global__ void fb_vmin_kernel(const double* __restrict__ best_v,
                               double* __restrict__ vmin, int* __restrict__ cnt,
                               double* __restrict__ loss_acc) {
    const int row = blockIdx.x * blockDim.x + threadIdx.x;
    if (row >= N_ROWS) return;
    if (row == 0) *loss_acc = 0.0;
    double v = best_v[(size_t)row * FB_SPLITK];
#pragma unroll
    for (int sp = 1; sp < FB_SPLITK; ++sp) {
        double s = best_v[(size_t)row * FB_SPLITK + sp];
        if (s < v) v = s;
    }
    vmin[row] = v; cnt[row] = 0;
}

__global__ __launch_bounds__(256, 2)
void fb_collect_kernel(const float* __restrict__ x, const float* __restrict__ cb,
                       const double* __restrict__ vmin, int* __restrict__ cnt,
                       int* __restrict__ cand) {
    __shared__ double As[FB_TD][FB_TN];
    __shared__ double Bs[FB_TD][FB_TK];
    const int t = threadIdx.x, tx = t & 15, ty = t >> 4, sr = t & 63, sg = t >> 6;
    const int row0 = blockIdx.x * FB_TN, k0 = blockIdx.y * FB_KSPLIT;
    double vlim[4];
#pragma unroll
    for (int i = 0; i < 4; ++i) vlim[i] = vmin[row0 + ty + 16 * i] + FB_MARGIN;
    for (int kt = 0; kt < FB_KSPLIT / FB_TK; ++kt) {
        double acc[4][4];
#pragma unroll
        for (int i = 0; i < 4; ++i)
#pragma unroll
            for (int j = 0; j < 4; ++j) acc[i][j] = 0.0;
        for (int dc = 0; dc < D_DIM / FB_TD; ++dc) {
            __syncthreads();
            const float* ap = x  + (size_t)(row0 + sr) * D_DIM + dc * FB_TD + sg * 16;
            const float* bp = cb + (size_t)(k0 + kt * FB_TK + sr) * D_DIM + dc * FB_TD + sg * 16;
#pragma unroll
            for (int q = 0; q < 4; ++q) {
                float4 a = ((const float4*)ap)[q];
                float4 b = ((const float4*)bp)[q];
                const int db = sg * 16 + q * 4;
                As[db + 0][sr] = a.x; As[db + 1][sr] = a.y; As[db + 2][sr] = a.z; As[db + 3][sr] = a.w;
                Bs[db + 0][sr] = b.x; Bs[db + 1][sr] = b.y; Bs[db + 2][sr] = b.z; Bs[db + 3][sr] = b.w;
            }
            __syncthreads();
#pragma unroll 8
            for (int d = 0; d < FB_TD; ++d) {
                double av[4], bv[4];
#pragma unroll
                for (int i = 0; i < 4; ++i) av[i] = As[d][ty + 16 * i];
#pragma unroll
                for (int j = 0; j < 4; ++j) bv[j] = Bs[d][tx + 16 * j];
#pragma unroll
                for (int i = 0; i < 4; ++i)
#pragma unroll
                    for (int j = 0; j < 4; ++j) acc[i][j] = fma(av[i], bv[j], acc[i][j]);
            }
        }
#pragma unroll
        for (int i = 0; i < 4; ++i) {
            const int row = row0 + ty + 16 * i;
#pragma unroll
            for (int j = 0; j < 4; ++j) {
                const double v = -2.0 * acc[i][j];
                if (v <= vlim[i]) {
                    const int k = k0 + kt * FB_TK + tx + 16 * j;
                    int pos = atomicAdd(&cnt[row], 1);
                    if (pos < FB_CAP) cand[(size_t)row * FB_CAP + pos] = k;
                }
            }
        }
        __syncthreads();
    }
}

__global__ void fb_decide_kernel(const float* __restrict__ x, const float* __restrict__ cb,
                                 const int* __restrict__ cnt, const int* __restrict__ cand,
                                 int* __restrict__ idx_i, float* __restrict__ idx_f) {
    const int row = blockIdx.x * blockDim.x + threadIdx.x;
    if (row >= N_ROWS) return;
    int c = cnt[row]; if (c > FB_CAP) c = FB_CAP;
    int win;
    if (c == 1) {
        win = cand[(size_t)row * FB_CAP];
    } else {
        const float* zr = x + (size_t)row * D_DIM;
        const float sn = __fadd_rn(__fadd_rn(np_pair128_sq(zr),       np_pair128_sq(zr + 128)),
                                   __fadd_rn(np_pair128_sq(zr + 256), np_pair128_sq(zr + 384)));
        float bd = 0.f; win = -1;
        for (int u = 0; u < c; ++u) {
            const int k = cand[(size_t)row * FB_CAP + u];
            const float e = np_einsum_dot(zr, cb + (size_t)k * D_DIM);
            const float dist = __fadd_rn(sn, __fmul_rn(-2.0f, e));
            if (win < 0 || dist < bd || (dist == bd && k < win)) { bd = dist; win = k; }
        }
    }
    idx_i[row] = win;
    idx_f[row] = (float)win;
}

extern "C" void kernel_launch(void* const* d_in, const int* in_sizes, int n_in,
                              void* d_out, int out_size, void* d_ws, size_t ws_size,
                              hipStream_t stream) {
    const float* x  = (const float*)d_in[0];   // [16384, 512]
    const float* cb = (const float*)d_in[1];   // [8192, 512]
    float* out    = (float*)d_out;
    float* zq     = out;
    float* losses = out + (size_t)N_ROWS * D_DIM;
    float* idx_f  = losses + 2;
    char* ws = (char*)d_ws;

    if (ws_size >= (7u << 20)) {
        // ---- fast MFMA-screen path (6.63 MB ws) ----
        float*  g_dmax   = (float*)(ws);                          // 2 MB
        uchar*  g_cnt    = (uchar*)(ws + (2u << 20));             // 512 KB
        uchar*  g_cand   = (uchar*)(ws + (2560u << 10));          // 4 MB
        int*    idx_i    = (int*)  (ws + (6656u << 10));          // 64 KB
        double* loss_acc = (double*)(ws + (6720u << 10));         // 8 B

        hipLaunchKernelGGL(vq_screen, dim3(K_CODES / 256, N_ROWS / 128), dim3(256), 0, stream,
                           x, cb, g_dmax, g_cnt, g_cand);
        hipLaunchKernelGGL(vq_decide, dim3(N_ROWS / 4), dim3(256), 0, stream,
                           x, cb, g_dmax, g_cnt, g_cand, idx_i, idx_f, loss_acc);
        hipLaunchKernelGGL(vq_gather_kernel, dim3(N_ROWS), dim3(128), 0, stream,
                           x, cb, idx_i, zq, loss_acc);
        hipLaunchKernelGGL(vq_finalize_kernel, dim3(1), dim3(1), 0, stream,
                           loss_acc, losses);
    } else {
        // ---- round-2-proven fp64 path (2.83 MB ws) ----
        double* best_v   = (double*)(ws);                          // 512 KB
        double* vmin     = (double*)(ws + (512 << 10));            // 128 KB
        int*    cnt      = (int*)   (ws + (640 << 10));            // 64 KB
        int*    cand     = (int*)   (ws + (704 << 10));            // 2 MB
        double* loss_acc = (double*)(ws + (2752 << 10));           // 8 B
        int*    idx_i    = (int*)   (ws + (2753 << 10));           // 64 KB

        hipLaunchKernelGGL(fb_min_kernel, dim3(N_ROWS / FB_TN, FB_SPLITK), dim3(256), 0, stream,
                           x, cb, best_v);
        hipLaunchKernelGGL(fb_vmin_kernel, dim3(N_ROWS / 256), dim3(256), 0, stream,
                           best_v, vmin, cnt, loss_acc);
        hipLaunchKernelGGL(fb_collect_kernel, dim3(N_ROWS / FB_TN, FB_SPLITK), dim3(256), 0, stream,
                           x, cb, vmin, cnt, cand);
        hipLaunchKernelGGL(fb_decide_kernel, dim3(N_ROWS / 256), dim3(256), 0, stream,
                           x, cb, cnt, cand, idx_i, idx_f);
        hipLaunchKernelGGL(vq_gather_kernel, dim3(N_ROWS), dim3(128), 0, stream,
                           x, cb, idx_i, zq, loss_acc);
        hipLaunchKernelGGL(vq_finalize_kernel, dim3(1), dim3(1), 0, stream,
                           loss_acc, losses);
    }
}

// Round 5
// 656.772 us; speedup vs baseline: 14.2144x; 1.5198x over previous
//
#include <hip/hip_runtime.h>

#define K_CODES 8192
#define D_DIM   512
#define N_ROWS  16384
#define NSPLIT  32          /* code splits of 256 */
#define CAP     8
#define T2      2.0e-4f     /* dot-space margin: tie window 3.05e-5 + 2*bf16 err 3.2e-5, 3x slack */

typedef __attribute__((ext_vector_type(8))) short bf16x8;
typedef __attribute__((ext_vector_type(4))) float f32x4;
typedef unsigned char uchar;
typedef unsigned short ushort;

// order-preserving float<->uint key (for unsigned atomicMax)
__device__ __forceinline__ unsigned fkey(float f) {
    unsigned b = __float_as_uint(f);
    return (b & 0x80000000u) ? ~b : (b | 0x80000000u);
}
__device__ __forceinline__ float finv(unsigned k) {
    return __uint_as_float((k & 0x80000000u) ? (k & 0x7fffffffu) : ~k);
}

// pack two floats to bf16 (RNE), low|high
__device__ __forceinline__ unsigned pk_bf16(float a, float b) {
    unsigned ua = __float_as_uint(a), ub = __float_as_uint(b);
    ua = (ua + 0x7fffu + ((ua >> 16) & 1u)) >> 16;
    ub = (ub + 0x7fffu + ((ub >> 16) & 1u)) & 0xffff0000u;
    return ua | ub;
}

// ---------------------------------------------------------------------------
// K0: pre-convert x and cb to bf16 (RNE) into workspace.
// ---------------------------------------------------------------------------
__global__ void vq_prepass(const float* __restrict__ x, const float* __restrict__ cb,
                           unsigned* __restrict__ xb, unsigned* __restrict__ cbb) {
    const size_t gid = (size_t)blockIdx.x * blockDim.x + threadIdx.x;
    const size_t nx = (size_t)N_ROWS * D_DIM / 8;     // 1048576
    const size_t nc = (size_t)K_CODES * D_DIM / 8;    // 524288
    if (gid < nx) {
        const float4 f0 = ((const float4*)x)[gid * 2];
        const float4 f1 = ((const float4*)x)[gid * 2 + 1];
        ((uint4*)xb)[gid] = make_uint4(pk_bf16(f0.x, f0.y), pk_bf16(f0.z, f0.w),
                                       pk_bf16(f1.x, f1.y), pk_bf16(f1.z, f1.w));
    } else if (gid < nx + nc) {
        const size_t g = gid - nx;
        const float4 f0 = ((const float4*)cb)[g * 2];
        const float4 f1 = ((const float4*)cb)[g * 2 + 1];
        ((uint4*)cbb)[g] = make_uint4(pk_bf16(f0.x, f0.y), pk_bf16(f0.z, f0.w),
                                      pk_bf16(f1.x, f1.y), pk_bf16(f1.z, f1.w));
    }
}

// ---------------------------------------------------------------------------
// K1: screening GEMM. Block = 128 rows x 256 codes, 4 waves each 64x128.
// Single bf16-hi MFMA per tile. LDS unpadded with XOR chunk swizzle:
// 16B chunk c of row r lives at slot c ^ ((r>>1)&3) -> uniform bank spread
// for both staging writes and frag reads.
// ---------------------------------------------------------------------------
template<bool PRE>
__global__ __launch_bounds__(256, 2)
void vq_screen2(const float* __restrict__ x, const float* __restrict__ cb,
                const ushort* __restrict__ xb, const ushort* __restrict__ cbb,
                float* __restrict__ g_dmax, uchar* __restrict__ g_cnt,
                uchar* __restrict__ g_cand) {
    __shared__ ushort Ash[128 * 32];    // 8 KB
    __shared__ ushort Bsh[256 * 32];    // 16 KB
    __shared__ unsigned vkey[128];
    __shared__ int ccnt[128];
    __shared__ uchar clist[128][CAP];

    const int t    = threadIdx.x;
    const int w    = t >> 6, lane = t & 63;
    const int fr   = lane & 15;
    const int quad = lane >> 4;
    const int wr   = (w & 1) * 64;          // wave row base
    const int wc   = (w >> 1) * 128;        // wave col base
    const int row0  = blockIdx.y * 128;
    const int kbase = blockIdx.x * 256;

    if (t < 128) { vkey[t] = 0u; ccnt[t] = 0; }

    // --- staging write addresses (constant across dc) ---
    const int r = t >> 1, h = t & 1;
    const int sA = (r >> 1) & 3;
    const int ca0 = (2 * h) ^ sA;
    ushort* awp0 = &Ash[r * 32 + ca0 * 8];
    ushort* awp1 = &Ash[r * 32 + (ca0 ^ 1) * 8];
    const int sB = (t >> 1) & 3;
    ushort* bwp0 = &Bsh[t * 32 + (0 ^ sB) * 8];
    ushort* bwp1 = &Bsh[t * 32 + (1 ^ sB) * 8];
    ushort* bwp2 = &Bsh[t * 32 + (2 ^ sB) * 8];
    ushort* bwp3 = &Bsh[t * 32 + (3 ^ sB) * 8];

    // --- frag read offsets (constant across dc) ---
    int aoff[4], boff[8];
#pragma unroll
    for (int i = 0; i < 4; ++i) {
        const int rw = wr + i * 16 + fr;
        aoff[i] = rw * 32 + ((quad ^ (rw >> 1)) & 3) * 8;
    }
#pragma unroll
    for (int j = 0; j < 8; ++j) {
        const int rw = wc + j * 16 + fr;
        boff[j] = rw * 32 + ((quad ^ (rw >> 1)) & 3) * 8;
    }

    // --- global base pointers ---
    const char* gA;
    const char* gB;
    if (PRE) {
        gA = (const char*)(xb  + (size_t)(row0 + r) * D_DIM + h * 16);
        gB = (const char*)(cbb + (size_t)(kbase + t) * D_DIM);
    } else {
        gA = (const char*)(x  + (size_t)(row0 + r) * D_DIM + h * 16);
        gB = (const char*)(cb + (size_t)(kbase + t) * D_DIM);
    }

    f32x4 acc[4][8];
#pragma unroll
    for (int i = 0; i < 4; ++i)
#pragma unroll
        for (int j = 0; j < 8; ++j) acc[i][j] = (f32x4)0.0f;

    for (int dc = 0; dc < D_DIM / 32; ++dc) {
        uint4 a0, a1, b0, b1, b2, b3;
        if (PRE) {
            a0 = *(const uint4*)(gA + dc * 64);
            a1 = *(const uint4*)(gA + dc * 64 + 16);
            b0 = *(const uint4*)(gB + dc * 64);
            b1 = *(const uint4*)(gB + dc * 64 + 16);
            b2 = *(const uint4*)(gB + dc * 64 + 32);
            b3 = *(const uint4*)(gB + dc * 64 + 48);
        } else {
            const float4* fa = (const float4*)(gA + dc * 128);
            float4 f0 = fa[0], f1 = fa[1], f2 = fa[2], f3 = fa[3];
            a0 = make_uint4(pk_bf16(f0.x, f0.y), pk_bf16(f0.z, f0.w),
                            pk_bf16(f1.x, f1.y), pk_bf16(f1.z, f1.w));
            a1 = make_uint4(pk_bf16(f2.x, f2.y), pk_bf16(f2.z, f2.w),
                            pk_bf16(f3.x, f3.y), pk_bf16(f3.z, f3.w));
            const float4* fb = (const float4*)(gB + dc * 128);
            float4 g0 = fb[0], g1 = fb[1], g2 = fb[2], g3 = fb[3];
            float4 g4 = fb[4], g5 = fb[5], g6 = fb[6], g7 = fb[7];
            b0 = make_uint4(pk_bf16(g0.x, g0.y), pk_bf16(g0.z, g0.w),
                            pk_bf16(g1.x, g1.y), pk_bf16(g1.z, g1.w));
            b1 = make_uint4(pk_bf16(g2.x, g2.y), pk_bf16(g2.z, g2.w),
                            pk_bf16(g3.x, g3.y), pk_bf16(g3.z, g3.w));
            b2 = make_uint4(pk_bf16(g4.x, g4.y), pk_bf16(g4.z, g4.w),
                            pk_bf16(g5.x, g5.y), pk_bf16(g5.z, g5.w));
            b3 = make_uint4(pk_bf16(g6.x, g6.y), pk_bf16(g6.z, g6.w),
                            pk_bf16(g7.x, g7.y), pk_bf16(g7.z, g7.w));
        }
        __syncthreads();
        *(uint4*)awp0 = a0; *(uint4*)awp1 = a1;
        *(uint4*)bwp0 = b0; *(uint4*)bwp1 = b1;
        *(uint4*)bwp2 = b2; *(uint4*)bwp3 = b3;
        __syncthreads();
        bf16x8 af[4], bfv[8];
#pragma unroll
        for (int i = 0; i < 4; ++i) af[i] = *(const bf16x8*)&Ash[aoff[i]];
#pragma unroll
        for (int j = 0; j < 8; ++j) bfv[j] = *(const bf16x8*)&Bsh[boff[j]];
#pragma unroll
        for (int i = 0; i < 4; ++i)
#pragma unroll
            for (int j = 0; j < 8; ++j)
                acc[i][j] = __builtin_amdgcn_mfma_f32_16x16x32_bf16(af[i], bfv[j], acc[i][j], 0, 0, 0);
    }

    // --- epilogue: per-row split max, then candidate push ---
    __syncthreads();
#pragma unroll
    for (int i = 0; i < 4; ++i)
#pragma unroll
        for (int rg = 0; rg < 4; ++rg) {
            float m = acc[i][0][rg];
#pragma unroll
            for (int j = 1; j < 8; ++j) m = fmaxf(m, acc[i][j][rg]);
            m = fmaxf(m, __shfl_xor(m, 1));
            m = fmaxf(m, __shfl_xor(m, 2));
            m = fmaxf(m, __shfl_xor(m, 4));
            m = fmaxf(m, __shfl_xor(m, 8));
            if (fr == 0) atomicMax(&vkey[wr + i * 16 + quad * 4 + rg], fkey(m));
        }
    __syncthreads();
#pragma unroll
    for (int i = 0; i < 4; ++i)
#pragma unroll
        for (int rg = 0; rg < 4; ++rg) {
            const int row = wr + i * 16 + quad * 4 + rg;
            const float thr = finv(vkey[row]) - T2;
#pragma unroll
            for (int j = 0; j < 8; ++j) {
                if (acc[i][j][rg] >= thr) {
                    int p = atomicAdd(&ccnt[row], 1);
                    if (p < CAP) clist[row][p] = (uchar)(wc + j * 16 + fr);
                }
            }
        }
    __syncthreads();
    if (t < 128) {
        const size_t o = (size_t)(row0 + t) * NSPLIT + blockIdx.x;
        g_dmax[o] = finv(vkey[t]);
        int c = ccnt[t];
        g_cnt[o] = (uchar)(c > 255 ? 255 : c);
        ((uint2*)g_cand)[o] = *(const uint2*)clist[t];
    }
}

// ---------------------------------------------------------------------------
// bit-exact numpy fp32 (baseline SSE3) replay — validated absmax=0 (r2, r4)
// ---------------------------------------------------------------------------
__device__ __forceinline__ float np_pair128_sq(const float* __restrict__ a) {
    float r[8];
#pragma unroll
    for (int j = 0; j < 8; ++j) r[j] = __fmul_rn(a[j], a[j]);
    for (int i = 8; i < 128; i += 8)
#pragma unroll
        for (int j = 0; j < 8; ++j) r[j] = __fadd_rn(r[j], __fmul_rn(a[i + j], a[i + j]));
    return __fadd_rn(__fadd_rn(__fadd_rn(r[0], r[1]), __fadd_rn(r[2], r[3])),
                     __fadd_rn(__fadd_rn(r[4], r[5]), __fadd_rn(r[6], r[7])));
}

__device__ __forceinline__ float np_einsum_dot(const float* __restrict__ a,
                                               const float* __restrict__ b) {
    float S0 = 0.f, S1 = 0.f, S2 = 0.f, S3 = 0.f;
    for (int i = 0; i < D_DIM; i += 16) {
        S0 = __fadd_rn(S0, __fmul_rn(a[i + 12], b[i + 12]));
        S1 = __fadd_rn(S1, __fmul_rn(a[i + 13], b[i + 13]));
        S2 = __fadd_rn(S2, __fmul_rn(a[i + 14], b[i + 14]));
        S3 = __fadd_rn(S3, __fmul_rn(a[i + 15], b[i + 15]));
        S0 = __fadd_rn(S0, __fmul_rn(a[i +  8], b[i +  8]));
        S1 = __fadd_rn(S1, __fmul_rn(a[i +  9], b[i +  9]));
        S2 = __fadd_rn(S2, __fmul_rn(a[i + 10], b[i + 10]));
        S3 = __fadd_rn(S3, __fmul_rn(a[i + 11], b[i + 11]));
        S0 = __fadd_rn(S0, __fmul_rn(a[i +  4], b[i +  4]));
        S1 = __fadd_rn(S1, __fmul_rn(a[i +  5], b[i +  5]));
        S2 = __fadd_rn(S2, __fmul_rn(a[i +  6], b[i +  6]));
        S3 = __fadd_rn(S3, __fmul_rn(a[i +  7], b[i +  7]));
        S0 = __fadd_rn(S0, __fmul_rn(a[i +  0], b[i +  0]));
        S1 = __fadd_rn(S1, __fmul_rn(a[i +  1], b[i +  1]));
        S2 = __fadd_rn(S2, __fmul_rn(a[i +  2], b[i +  2]));
        S3 = __fadd_rn(S3, __fmul_rn(a[i +  3], b[i +  3]));
    }
    return __fadd_rn(__fadd_rn(S0, S1), __fadd_rn(S2, S3));
}

// ---------------------------------------------------------------------------
// K2: wave-per-row decide; lane-parallel candidate replay; cap-overflow ->
// exact replay of the full 256-code split (coverage from split maxima only).
// ---------------------------------------------------------------------------
__global__ __launch_bounds__(256)
void vq_decide(const float* __restrict__ x, const float* __restrict__ cb,
               const float* __restrict__ g_dmax, const uchar* __restrict__ g_cnt,
               const uchar* __restrict__ g_cand,
               int* __restrict__ idx_i, float* __restrict__ idx_f) {
    const int wv = threadIdx.x >> 6, lane = threadIdx.x & 63;
    const int row = blockIdx.x * 4 + wv;
    const float* dm = g_dmax + (size_t)row * NSPLIT;

    float g = dm[lane & 31];
    g = fmaxf(g, __shfl_xor(g, 1));
    g = fmaxf(g, __shfl_xor(g, 2));
    g = fmaxf(g, __shfl_xor(g, 4));
    g = fmaxf(g, __shfl_xor(g, 8));
    g = fmaxf(g, __shfl_xor(g, 16));
    const float thr = g - T2;

    const float* zr = x + (size_t)row * D_DIM;
    const float sn = __fadd_rn(__fadd_rn(np_pair128_sq(zr),       np_pair128_sq(zr + 128)),
                               __fadd_rn(np_pair128_sq(zr + 256), np_pair128_sq(zr + 384)));

    float bd = 3.4e38f;
    int   bk = 0x7fffffff;
    for (int s = 0; s < NSPLIT; ++s) {
        if (dm[s] < thr) continue;
        const size_t o = (size_t)row * NSPLIT + s;
        const int c = g_cnt[o];
        if (c <= CAP) {
            if (lane < c) {
                const int k = s * 256 + g_cand[o * CAP + lane];
                const float e = np_einsum_dot(zr, cb + (size_t)k * D_DIM);
                const float d = __fadd_rn(sn, __fmul_rn(-2.0f, e));
                if (d < bd || (d == bd && k < bk)) { bd = d; bk = k; }
            }
        } else {
            for (int u = 0; u < 4; ++u) {
                const int k = s * 256 + lane * 4 + u;
                const float e = np_einsum_dot(zr, cb + (size_t)k * D_DIM);
                const float d = __fadd_rn(sn, __fmul_rn(-2.0f, e));
                if (d < bd || (d == bd && k < bk)) { bd = d; bk = k; }
            }
        }
    }
#pragma unroll
    for (int off = 1; off < 64; off <<= 1) {
        const float od = __shfl_xor(bd, off);
        const int   ok = __shfl_xor(bk, off);
        if (od < bd || (od == bd && ok < bk)) { bd = od; bk = ok; }
    }
    if (lane == 0) { idx_i[row] = bk; idx_f[row] = (float)bk; }
}

// ---------------------------------------------------------------------------
// K3: gather z_q (exact fp32 straight-through arithmetic) + per-row loss
// partial (no atomics — psum array, reduced in finalize).
// ---------------------------------------------------------------------------
__global__ void vq_gather_kernel(const float* __restrict__ x,
                                 const float* __restrict__ cb,
                                 const int* __restrict__ idx,
                                 float* __restrict__ zq_out,
                                 double* __restrict__ psum) {
    const int row = blockIdx.x;
    const int t   = threadIdx.x;   // 128
    const int k   = idx[row];
    const float4 c  = ((const float4*)(cb + (size_t)k   * D_DIM))[t];
    const float4 xv = ((const float4*)(x  + (size_t)row * D_DIM))[t];
    float4 o;
    o.x = __fadd_rn(xv.x, __fsub_rn(c.x, xv.x));
    o.y = __fadd_rn(xv.y, __fsub_rn(c.y, xv.y));
    o.z = __fadd_rn(xv.z, __fsub_rn(c.z, xv.z));
    o.w = __fadd_rn(xv.w, __fsub_rn(c.w, xv.w));
    ((float4*)(zq_out + (size_t)row * D_DIM))[t] = o;
    const double d0 = (double)c.x - (double)xv.x;
    const double d1 = (double)c.y - (double)xv.y;
    const double d2 = (double)c.z - (double)xv.z;
    const double d3 = (double)c.w - (double)xv.w;
    double s = d0 * d0 + d1 * d1 + d2 * d2 + d3 * d3;
#pragma unroll
    for (int off = 32; off > 0; off >>= 1) s += __shfl_xor(s, off, 64);
    __shared__ double red[2];
    if ((t & 63) == 0) red[t >> 6] = s;
    __syncthreads();
    if (t == 0) psum[row] = red[0] + red[1];
}

// ---------------------------------------------------------------------------
// K4: reduce psum -> losses.
// ---------------------------------------------------------------------------
__global__ void vq_finalize2(const double* __restrict__ psum,
                             float* __restrict__ losses) {
    __shared__ double red[4];
    const int t = threadIdx.x;   // 256
    double s = 0.0;
    for (int i = t; i < N_ROWS; i += 256) s += psum[i];
#pragma unroll
    for (int off = 32; off > 0; off >>= 1) s += __shfl_xor(s, off, 64);
    if ((t & 63) == 0) red[t >> 6] = s;
    __syncthreads();
    if (t == 0) {
        const double tot = red[0] + red[1] + red[2] + red[3];
        const float l = (float)(tot / (double)((size_t)N_ROWS * D_DIM));
        losses[0] = l;
        losses[1] = l;
    }
}

extern "C" void kernel_launch(void* const* d_in, const int* in_sizes, int n_in,
                              void* d_out, int out_size, void* d_ws, size_t ws_size,
                              hipStream_t stream) {
    const float* x  = (const float*)d_in[0];   // [16384, 512]
    const float* cb = (const float*)d_in[1];   // [8192, 512]
    float* out    = (float*)d_out;
    float* zq     = out;
    float* losses = out + (size_t)N_ROWS * D_DIM;
    float* idx_f  = losses + 2;
    char* ws = (char*)d_ws;

    const bool pre = (ws_size >= ((size_t)31 << 20));
    char* base = pre ? (ws + ((size_t)24 << 20)) : ws;

    float*  g_dmax = (float*)(base);                             // 2 MB
    uchar*  g_cnt  = (uchar*)(base + (2u << 20));                // 512 KB
    uchar*  g_cand = (uchar*)(base + (2560u << 10));             // 4 MB
    int*    idx_i  = (int*)  (base + (6656u << 10));             // 64 KB
    double* psum   = (double*)(base + (6720u << 10));            // 128 KB

    if (pre) {
        ushort* xb  = (ushort*)ws;                               // 16 MB
        ushort* cbb = (ushort*)(ws + ((size_t)16 << 20));        // 8 MB
        hipLaunchKernelGGL(vq_prepass, dim3(6144), dim3(256), 0, stream,
                           x, cb, (unsigned*)xb, (unsigned*)cbb);
        hipLaunchKernelGGL((vq_screen2<true>), dim3(K_CODES / 256, N_ROWS / 128), dim3(256), 0, stream,
                           x, cb, xb, cbb, g_dmax, g_cnt, g_cand);
    } else {
        hipLaunchKernelGGL((vq_screen2<false>), dim3(K_CODES / 256, N_ROWS / 128), dim3(256), 0, stream,
                           x, cb, (const ushort*)nullptr, (const ushort*)nullptr,
                           g_dmax, g_cnt, g_cand);
    }
    hipLaunchKernelGGL(vq_decide, dim3(N_ROWS / 4), dim3(256), 0, stream,
                       x, cb, g_dmax, g_cnt, g_cand, idx_i, idx_f);
    hipLaunchKernelGGL(vq_gather_kernel, dim3(N_ROWS), dim3(128), 0, stream,
                       x, cb, idx_i, zq, psum);
    hipLaunchKernelGGL(vq_finalize2, dim3(1), dim3(256), 0, stream,
                       psum, losses);
}

// Round 6
// 508.524 us; speedup vs baseline: 18.3582x; 1.2915x over previous
//
#include <hip/hip_runtime.h>

#define K_CODES 8192
#define D_DIM   512
#define N_ROWS  16384
#define NSPLIT  32          /* code splits of 256 */
#define CAP     8
#define T2      2.0e-4f     /* dot-space margin (validated r4/r5) */
#define LIST_CAP 32768

typedef __attribute__((ext_vector_type(8))) short bf16x8;
typedef __attribute__((ext_vector_type(4))) float f32x4;
typedef unsigned char uchar;
typedef unsigned short ushort;
typedef unsigned long long u64;

// order-preserving float<->uint key (for unsigned atomicMax/Min)
__device__ __forceinline__ unsigned fkey(float f) {
    unsigned b = __float_as_uint(f);
    return (b & 0x80000000u) ? ~b : (b | 0x80000000u);
}
__device__ __forceinline__ float finv(unsigned k) {
    return __uint_as_float((k & 0x80000000u) ? (k & 0x7fffffffu) : ~k);
}

// pack two floats to bf16 (RNE), low|high
__device__ __forceinline__ unsigned pk_bf16(float a, float b) {
    unsigned ua = __float_as_uint(a), ub = __float_as_uint(b);
    ua = (ua + 0x7fffu + ((ua >> 16) & 1u)) >> 16;
    ub = (ub + 0x7fffu + ((ub >> 16) & 1u)) & 0xffff0000u;
    return ua | ub;
}

// ---------------------------------------------------------------------------
// K0: pre-convert x and cb to bf16 (RNE) into workspace.
// ---------------------------------------------------------------------------
__global__ void vq_prepass(const float* __restrict__ x, const float* __restrict__ cb,
                           unsigned* __restrict__ xb, unsigned* __restrict__ cbb) {
    const size_t gid = (size_t)blockIdx.x * blockDim.x + threadIdx.x;
    const size_t nx = (size_t)N_ROWS * D_DIM / 8;
    const size_t nc = (size_t)K_CODES * D_DIM / 8;
    if (gid < nx) {
        const float4 f0 = ((const float4*)x)[gid * 2];
        const float4 f1 = ((const float4*)x)[gid * 2 + 1];
        ((uint4*)xb)[gid] = make_uint4(pk_bf16(f0.x, f0.y), pk_bf16(f0.z, f0.w),
                                       pk_bf16(f1.x, f1.y), pk_bf16(f1.z, f1.w));
    } else if (gid < nx + nc) {
        const size_t g = gid - nx;
        const float4 f0 = ((const float4*)cb)[g * 2];
        const float4 f1 = ((const float4*)cb)[g * 2 + 1];
        ((uint4*)cbb)[g] = make_uint4(pk_bf16(f0.x, f0.y), pk_bf16(f0.z, f0.w),
                                      pk_bf16(f1.x, f1.y), pk_bf16(f1.z, f1.w));
    }
}

// ---------------------------------------------------------------------------
// K1: screening GEMM (unchanged from r5 — validated). 128 rows x 256 codes,
// 4 waves of 64x128, single bf16-hi MFMA, XOR-swizzled LDS.
// ---------------------------------------------------------------------------
template<bool PRE>
__global__ __launch_bounds__(256, 2)
void vq_screen2(const float* __restrict__ x, const float* __restrict__ cb,
                const ushort* __restrict__ xb, const ushort* __restrict__ cbb,
                float* __restrict__ g_dmax, uchar* __restrict__ g_cnt,
                uchar* __restrict__ g_cand) {
    __shared__ ushort Ash[128 * 32];
    __shared__ ushort Bsh[256 * 32];
    __shared__ unsigned vkey[128];
    __shared__ int ccnt[128];
    __shared__ uchar clist[128][CAP];

    const int t    = threadIdx.x;
    const int w    = t >> 6, lane = t & 63;
    const int fr   = lane & 15;
    const int quad = lane >> 4;
    const int wr   = (w & 1) * 64;
    const int wc   = (w >> 1) * 128;
    const int row0  = blockIdx.y * 128;
    const int kbase = blockIdx.x * 256;

    if (t < 128) { vkey[t] = 0u; ccnt[t] = 0; }

    const int r = t >> 1, h = t & 1;
    const int sA = (r >> 1) & 3;
    const int ca0 = (2 * h) ^ sA;
    ushort* awp0 = &Ash[r * 32 + ca0 * 8];
    ushort* awp1 = &Ash[r * 32 + (ca0 ^ 1) * 8];
    const int sB = (t >> 1) & 3;
    ushort* bwp0 = &Bsh[t * 32 + (0 ^ sB) * 8];
    ushort* bwp1 = &Bsh[t * 32 + (1 ^ sB) * 8];
    ushort* bwp2 = &Bsh[t * 32 + (2 ^ sB) * 8];
    ushort* bwp3 = &Bsh[t * 32 + (3 ^ sB) * 8];

    int aoff[4], boff[8];
#pragma unroll
    for (int i = 0; i < 4; ++i) {
        const int rw = wr + i * 16 + fr;
        aoff[i] = rw * 32 + ((quad ^ (rw >> 1)) & 3) * 8;
    }
#pragma unroll
    for (int j = 0; j < 8; ++j) {
        const int rw = wc + j * 16 + fr;
        boff[j] = rw * 32 + ((quad ^ (rw >> 1)) & 3) * 8;
    }

    const char* gA;
    const char* gB;
    if (PRE) {
        gA = (const char*)(xb  + (size_t)(row0 + r) * D_DIM + h * 16);
        gB = (const char*)(cbb + (size_t)(kbase + t) * D_DIM);
    } else {
        gA = (const char*)(x  + (size_t)(row0 + r) * D_DIM + h * 16);
        gB = (const char*)(cb + (size_t)(kbase + t) * D_DIM);
    }

    f32x4 acc[4][8];
#pragma unroll
    for (int i = 0; i < 4; ++i)
#pragma unroll
        for (int j = 0; j < 8; ++j) acc[i][j] = (f32x4)0.0f;

    for (int dc = 0; dc < D_DIM / 32; ++dc) {
        uint4 a0, a1, b0, b1, b2, b3;
        if (PRE) {
            a0 = *(const uint4*)(gA + dc * 64);
            a1 = *(const uint4*)(gA + dc * 64 + 16);
            b0 = *(const uint4*)(gB + dc * 64);
            b1 = *(const uint4*)(gB + dc * 64 + 16);
            b2 = *(const uint4*)(gB + dc * 64 + 32);
            b3 = *(const uint4*)(gB + dc * 64 + 48);
        } else {
            const float4* fa = (const float4*)(gA + dc * 128);
            float4 f0 = fa[0], f1 = fa[1], f2 = fa[2], f3 = fa[3];
            a0 = make_uint4(pk_bf16(f0.x, f0.y), pk_bf16(f0.z, f0.w),
                            pk_bf16(f1.x, f1.y), pk_bf16(f1.z, f1.w));
            a1 = make_uint4(pk_bf16(f2.x, f2.y), pk_bf16(f2.z, f2.w),
                            pk_bf16(f3.x, f3.y), pk_bf16(f3.z, f3.w));
            const float4* fb = (const float4*)(gB + dc * 128);
            float4 g0 = fb[0], g1 = fb[1], g2 = fb[2], g3 = fb[3];
            float4 g4 = fb[4], g5 = fb[5], g6 = fb[6], g7 = fb[7];
            b0 = make_uint4(pk_bf16(g0.x, g0.y), pk_bf16(g0.z, g0.w),
                            pk_bf16(g1.x, g1.y), pk_bf16(g1.z, g1.w));
            b1 = make_uint4(pk_bf16(g2.x, g2.y), pk_bf16(g2.z, g2.w),
                            pk_bf16(g3.x, g3.y), pk_bf16(g3.z, g3.w));
            b2 = make_uint4(pk_bf16(g4.x, g4.y), pk_bf16(g4.z, g4.w),
                            pk_bf16(g5.x, g5.y), pk_bf16(g5.z, g5.w));
            b3 = make_uint4(pk_bf16(g6.x, g6.y), pk_bf16(g6.z, g6.w),
                            pk_bf16(g7.x, g7.y), pk_bf16(g7.z, g7.w));
        }
        __syncthreads();
        *(uint4*)awp0 = a0; *(uint4*)awp1 = a1;
        *(uint4*)bwp0 = b0; *(uint4*)bwp1 = b1;
        *(uint4*)bwp2 = b2; *(uint4*)bwp3 = b3;
        __syncthreads();
        bf16x8 af[4], bfv[8];
#pragma unroll
        for (int i = 0; i < 4; ++i) af[i] = *(const bf16x8*)&Ash[aoff[i]];
#pragma unroll
        for (int j = 0; j < 8; ++j) bfv[j] = *(const bf16x8*)&Bsh[boff[j]];
#pragma unroll
        for (int i = 0; i < 4; ++i)
#pragma unroll
            for (int j = 0; j < 8; ++j)
                acc[i][j] = __builtin_amdgcn_mfma_f32_16x16x32_bf16(af[i], bfv[j], acc[i][j], 0, 0, 0);
    }

    __syncthreads();
#pragma unroll
    for (int i = 0; i < 4; ++i)
#pragma unroll
        for (int rg = 0; rg < 4; ++rg) {
            float m = acc[i][0][rg];
#pragma unroll
            for (int j = 1; j < 8; ++j) m = fmaxf(m, acc[i][j][rg]);
            m = fmaxf(m, __shfl_xor(m, 1));
            m = fmaxf(m, __shfl_xor(m, 2));
            m = fmaxf(m, __shfl_xor(m, 4));
            m = fmaxf(m, __shfl_xor(m, 8));
            if (fr == 0) atomicMax(&vkey[wr + i * 16 + quad * 4 + rg], fkey(m));
        }
    __syncthreads();
#pragma unroll
    for (int i = 0; i < 4; ++i)
#pragma unroll
        for (int rg = 0; rg < 4; ++rg) {
            const int row = wr + i * 16 + quad * 4 + rg;
            const float thr = finv(vkey[row]) - T2;
#pragma unroll
            for (int j = 0; j < 8; ++j) {
                if (acc[i][j][rg] >= thr) {
                    int p = atomicAdd(&ccnt[row], 1);
                    if (p < CAP) clist[row][p] = (uchar)(wc + j * 16 + fr);
                }
            }
        }
    __syncthreads();
    if (t < 128) {
        const size_t o = (size_t)(row0 + t) * NSPLIT + blockIdx.x;
        g_dmax[o] = finv(vkey[t]);
        int c = ccnt[t];
        g_cnt[o] = (uchar)(c > 255 ? 255 : c);
        ((uint2*)g_cand)[o] = *(const uint2*)clist[t];
    }
}

// ---------------------------------------------------------------------------
// K2: exact per-row ||z||^2, numpy pairwise structure parallelized over 32
// lanes. Lane (b,j) runs the serial r[j]-chain of 128-block b; XOR-shuffle
// tree reproduces ((r0+r1)+(r2+r3))+((r4+r5)+(r6+r7)) then ((B0+B1)+(B2+B3))
// bit-exactly. Also zeroes list count and inits keys.
// ---------------------------------------------------------------------------
__global__ __launch_bounds__(256)
void vq_sn(const float* __restrict__ x, float* __restrict__ sn,
           u64* __restrict__ keys, int* __restrict__ count) {
    const int t = threadIdx.x;
    const int base = blockIdx.x * 8;
    if (blockIdx.x == 0 && t == 0) *count = 0;
    if (t < 8) keys[base + t] = ~0ull;
    const int wave = t >> 6, lane = t & 63;
    const int row = base + wave * 2 + (lane >> 5);
    const int l = lane & 31, b = l >> 3, j = l & 7;
    const float* a = x + (size_t)row * D_DIM + b * 128 + j;
    float r = __fmul_rn(a[0], a[0]);
#pragma unroll
    for (int i = 1; i < 16; ++i) {
        const float v = a[i * 8];
        r = __fadd_rn(r, __fmul_rn(v, v));
    }
    r = __fadd_rn(r, __shfl_xor(r, 1));
    r = __fadd_rn(r, __shfl_xor(r, 2));
    r = __fadd_rn(r, __shfl_xor(r, 4));
    r = __fadd_rn(r, __shfl_xor(r, 8));
    r = __fadd_rn(r, __shfl_xor(r, 16));
    if (l == 0) sn[row] = r;
}

// ---------------------------------------------------------------------------
// K3: thread-per-row shortlist build. Single-candidate rows resolve here;
// multi-candidate rows emit (row,k) list entries; overflow splits expand to
// all 256 codes (coverage backstop).
// ---------------------------------------------------------------------------
__global__ __launch_bounds__(256)
void vq_build(const float* __restrict__ g_dmax, const uchar* __restrict__ g_cnt,
              const uchar* __restrict__ g_cand, int2* __restrict__ list,
              int* __restrict__ count, float* __restrict__ idx_f) {
    const int row = blockIdx.x * blockDim.x + threadIdx.x;
    const float* dm = g_dmax + (size_t)row * NSPLIT;
    float g = dm[0];
#pragma unroll
    for (int s = 1; s < NSPLIT; ++s) g = fmaxf(g, dm[s]);
    const float thr = g - T2;

    int tot = 0, first = -1;
    for (int s = 0; s < NSPLIT; ++s) {
        if (dm[s] < thr) continue;
        const size_t o = (size_t)row * NSPLIT + s;
        const int c = g_cnt[o];
        tot += (c > CAP) ? 256 : c;
        if (first < 0) first = s * 256 + g_cand[o * CAP];
    }
    idx_f[row] = (float)first;         // final for tot==1; fallback otherwise
    if (tot <= 1) return;

    for (int s = 0; s < NSPLIT; ++s) {
        if (dm[s] < thr) continue;
        const size_t o = (size_t)row * NSPLIT + s;
        const int c = g_cnt[o];
        if (c > CAP) {
            int pos = atomicAdd(count, 256);
            for (int u = 0; u < 256 && pos + u < LIST_CAP; ++u)
                list[pos + u] = make_int2(row, s * 256 + u);
        } else {
            int pos = atomicAdd(count, c);
            for (int u = 0; u < c && pos + u < LIST_CAP; ++u)
                list[pos + u] = make_int2(row, s * 256 + g_cand[o * CAP + u]);
        }
    }
}

// bit-exact numpy fp32 (baseline SSE3) einsum — validated absmax=0 (r2,r4,r5)
__device__ __forceinline__ float np_einsum_dot(const float* __restrict__ a,
                                               const float* __restrict__ b) {
    float S0 = 0.f, S1 = 0.f, S2 = 0.f, S3 = 0.f;
    for (int i = 0; i < D_DIM; i += 16) {
        S0 = __fadd_rn(S0, __fmul_rn(a[i + 12], b[i + 12]));
        S1 = __fadd_rn(S1, __fmul_rn(a[i + 13], b[i + 13]));
        S2 = __fadd_rn(S2, __fmul_rn(a[i + 14], b[i + 14]));
        S3 = __fadd_rn(S3, __fmul_rn(a[i + 15], b[i + 15]));
        S0 = __fadd_rn(S0, __fmul_rn(a[i +  8], b[i +  8]));
        S1 = __fadd_rn(S1, __fmul_rn(a[i +  9], b[i +  9]));
        S2 = __fadd_rn(S2, __fmul_rn(a[i + 10], b[i + 10]));
        S3 = __fadd_rn(S3, __fmul_rn(a[i + 11], b[i + 11]));
        S0 = __fadd_rn(S0, __fmul_rn(a[i +  4], b[i +  4]));
        S1 = __fadd_rn(S1, __fmul_rn(a[i +  5], b[i +  5]));
        S2 = __fadd_rn(S2, __fmul_rn(a[i +  6], b[i +  6]));
        S3 = __fadd_rn(S3, __fmul_rn(a[i +  7], b[i +  7]));
        S0 = __fadd_rn(S0, __fmul_rn(a[i +  0], b[i +  0]));
        S1 = __fadd_rn(S1, __fmul_rn(a[i +  1], b[i +  1]));
        S2 = __fadd_rn(S2, __fmul_rn(a[i +  2], b[i +  2]));
        S3 = __fadd_rn(S3, __fmul_rn(a[i +  3], b[i +  3]));
    }
    return __fadd_rn(__fadd_rn(S0, S1), __fadd_rn(S2, S3));
}

// ---------------------------------------------------------------------------
// K4: lane-per-entry exact replay; atomicMin on packed (distKey<<32)|k gives
// min-dist with first-index tie semantics.
// ---------------------------------------------------------------------------
__global__ __launch_bounds__(256)
void vq_replay(const float* __restrict__ x, const float* __restrict__ cb,
               const float* __restrict__ sn, const int2* __restrict__ list,
               const int* __restrict__ count, u64* __restrict__ keys) {
    const int i = blockIdx.x * blockDim.x + threadIdx.x;
    int n = *count; if (n > LIST_CAP) n = LIST_CAP;
    if (i >= n) return;
    const int2 e = list[i];
    const float* zr = x + (size_t)e.x * D_DIM;
    const float d = __fadd_rn(sn[e.x],
                              __fmul_rn(-2.0f, np_einsum_dot(zr, cb + (size_t)e.y * D_DIM)));
    const u64 key = ((u64)fkey(d) << 32) | (unsigned)e.y;
    atomicMin(&keys[e.x], key);
}

// ---------------------------------------------------------------------------
// K5: resolve replayed rows.
// ---------------------------------------------------------------------------
__global__ __launch_bounds__(256)
void vq_resolve(const u64* __restrict__ keys, float* __restrict__ idx_f) {
    const int row = blockIdx.x * blockDim.x + threadIdx.x;
    const u64 k = keys[row];
    if (k != ~0ull) idx_f[row] = (float)(int)(k & 0xffffffffu);
}

// ---------------------------------------------------------------------------
// K6: gather z_q (exact fp32 straight-through) + per-row loss partial.
// ---------------------------------------------------------------------------
__global__ void vq_gather_kernel(const float* __restrict__ x,
                                 const float* __restrict__ cb,
                                 const float* __restrict__ idx_f,
                                 float* __restrict__ zq_out,
                                 double* __restrict__ psum) {
    const int row = blockIdx.x;
    const int t   = threadIdx.x;   // 128
    const int k   = (int)idx_f[row];
    const float4 c  = ((const float4*)(cb + (size_t)k   * D_DIM))[t];
    const float4 xv = ((const float4*)(x  + (size_t)row * D_DIM))[t];
    float4 o;
    o.x = __fadd_rn(xv.x, __fsub_rn(c.x, xv.x));
    o.y = __fadd_rn(xv.y, __fsub_rn(c.y, xv.y));
    o.z = __fadd_rn(xv.z, __fsub_rn(c.z, xv.z));
    o.w = __fadd_rn(xv.w, __fsub_rn(c.w, xv.w));
    ((float4*)(zq_out + (size_t)row * D_DIM))[t] = o;
    const double d0 = (double)c.x - (double)xv.x;
    const double d1 = (double)c.y - (double)xv.y;
    const double d2 = (double)c.z - (double)xv.z;
    const double d3 = (double)c.w - (double)xv.w;
    double s = d0 * d0 + d1 * d1 + d2 * d2 + d3 * d3;
#pragma unroll
    for (int off = 32; off > 0; off >>= 1) s += __shfl_xor(s, off, 64);
    __shared__ double red[2];
    if ((t & 63) == 0) red[t >> 6] = s;
    __syncthreads();
    if (t == 0) psum[row] = red[0] + red[1];
}

__global__ void vq_finalize2(const double* __restrict__ psum,
                             float* __restrict__ losses) {
    __shared__ double red[4];
    const int t = threadIdx.x;   // 256
    double s = 0.0;
    for (int i = t; i < N_ROWS; i += 256) s += psum[i];
#pragma unroll
    for (int off = 32; off > 0; off >>= 1) s += __shfl_xor(s, off, 64);
    if ((t & 63) == 0) red[t >> 6] = s;
    __syncthreads();
    if (t == 0) {
        const double tot = red[0] + red[1] + red[2] + red[3];
        const float l = (float)(tot / (double)((size_t)N_ROWS * D_DIM));
        losses[0] = l;
        losses[1] = l;
    }
}

extern "C" void kernel_launch(void* const* d_in, const int* in_sizes, int n_in,
                              void* d_out, int out_size, void* d_ws, size_t ws_size,
                              hipStream_t stream) {
    const float* x  = (const float*)d_in[0];   // [16384, 512]
    const float* cb = (const float*)d_in[1];   // [8192, 512]
    float* out    = (float*)d_out;
    float* zq     = out;
    float* losses = out + (size_t)N_ROWS * D_DIM;
    float* idx_f  = losses + 2;
    char* ws = (char*)d_ws;

    const bool pre = (ws_size >= ((size_t)31 << 20));
    char* base = pre ? (ws + ((size_t)24 << 20)) : ws;

    // base layout (7 MB total):
    float*  g_dmax = (float*)(base);                     // 2048 KB
    uchar*  g_cnt  = (uchar*)(base + (2048u << 10));     //  512 KB
    uchar*  g_cand = (uchar*)(base + (2560u << 10));     // 4096 KB
    float*  sn     = (float*)(base + (6656u << 10));     //   64 KB
    u64*    keys   = (u64*)  (base + (6720u << 10));     //  128 KB (psum overlay)
    int2*   list   = (int2*) (base + (6848u << 10));     //  256 KB
    int*    count  = (int*)  (base + (7104u << 10));     //    4 B
    double* psum   = (double*)keys;                      // overlay (after resolve)

    if (pre) {
        ushort* xb  = (ushort*)ws;                               // 16 MB
        ushort* cbb = (ushort*)(ws + ((size_t)16 << 20));        // 8 MB
        hipLaunchKernelGGL(vq_prepass, dim3(6144), dim3(256), 0, stream,
                           x, cb, (unsigned*)xb, (unsigned*)cbb);
        hipLaunchKernelGGL((vq_screen2<true>), dim3(K_CODES / 256, N_ROWS / 128), dim3(256), 0, stream,
                           x, cb, xb, cbb, g_dmax, g_cnt, g_cand);
    } else {
        hipLaunchKernelGGL((vq_screen2<false>), dim3(K_CODES / 256, N_ROWS / 128), dim3(256), 0, stream,
                           x, cb, (const ushort*)nullptr, (const ushort*)nullptr,
                           g_dmax, g_cnt, g_cand);
    }
    hipLaunchKernelGGL(vq_sn, dim3(N_ROWS / 8), dim3(256), 0, stream,
                       x, sn, keys, count);
    hipLaunchKernelGGL(vq_build, dim3(N_ROWS / 256), dim3(256), 0, stream,
                       g_dmax, g_cnt, g_cand, list, count, idx_f);
    hipLaunchKernelGGL(vq_replay, dim3(LIST_CAP / 256), dim3(256), 0, stream,
                       x, cb, sn, list, count, keys);
    hipLaunchKernelGGL(vq_resolve, dim3(N_ROWS / 256), dim3(256), 0, stream,
                       keys, idx_f);
    hipLaunchKernelGGL(vq_gather_kernel, dim3(N_ROWS), dim3(128), 0, stream,
                       x, cb, idx_f, zq, psum);
    hipLaunchKernelGGL(vq_finalize2, dim3(1), dim3(256), 0, stream,
                       psum, losses);
}

// Round 7
// 396.805 us; speedup vs baseline: 23.5269x; 1.2815x over previous
//
#include <hip/hip_runtime.h>

#define K_CODES 8192
#define D_DIM   512
#define N_ROWS  16384
#define NSPLIT  32          /* code splits of 256 */
#define CAP     8
#define T2      2.0e-4f     /* dot-space margin (validated r4-r6) */
#define LIST_CAP 32768

typedef __attribute__((ext_vector_type(8))) short bf16x8;
typedef __attribute__((ext_vector_type(4))) float f32x4;
typedef unsigned char uchar;
typedef unsigned short ushort;
typedef unsigned long long u64;

__device__ __forceinline__ unsigned fkey(float f) {
    unsigned b = __float_as_uint(f);
    return (b & 0x80000000u) ? ~b : (b | 0x80000000u);
}
__device__ __forceinline__ float finv(unsigned k) {
    return __uint_as_float((k & 0x80000000u) ? (k & 0x7fffffffu) : ~k);
}

__device__ __forceinline__ unsigned pk_bf16(float a, float b) {
    unsigned ua = __float_as_uint(a), ub = __float_as_uint(b);
    ua = (ua + 0x7fffu + ((ua >> 16) & 1u)) >> 16;
    ub = (ub + 0x7fffu + ((ub >> 16) & 1u)) & 0xffff0000u;
    return ua | ub;
}

// ---------------------------------------------------------------------------
// K0 (pre path): bf16 conversion of x/cb  +  fused exact ||z||^2 (numpy
// pairwise bit-exact, 32-lane parallel)  +  keys/count init.
// Blocks [0,6144): conversion; [6144,8192): sn+init.
// ---------------------------------------------------------------------------
__global__ void vq_prepass(const float* __restrict__ x, const float* __restrict__ cb,
                           unsigned* __restrict__ xb, unsigned* __restrict__ cbb,
                           float* __restrict__ sn, u64* __restrict__ keys,
                           int* __restrict__ count) {
    const int bid = blockIdx.x;
    const int t = threadIdx.x;
    if (bid < 6144) {
        const size_t gid = (size_t)bid * 256 + t;
        const size_t nx = (size_t)N_ROWS * D_DIM / 8;     // 1048576
        if (gid < nx) {
            const float4 f0 = ((const float4*)x)[gid * 2];
            const float4 f1 = ((const float4*)x)[gid * 2 + 1];
            ((uint4*)xb)[gid] = make_uint4(pk_bf16(f0.x, f0.y), pk_bf16(f0.z, f0.w),
                                           pk_bf16(f1.x, f1.y), pk_bf16(f1.z, f1.w));
        } else {
            const size_t g = gid - nx;
            const float4 f0 = ((const float4*)cb)[g * 2];
            const float4 f1 = ((const float4*)cb)[g * 2 + 1];
            ((uint4*)cbb)[g] = make_uint4(pk_bf16(f0.x, f0.y), pk_bf16(f0.z, f0.w),
                                          pk_bf16(f1.x, f1.y), pk_bf16(f1.z, f1.w));
        }
    } else {
        const int base = (bid - 6144) * 8;
        if (bid == 6144 && t == 0) *count = 0;
        if (t < 8) keys[base + t] = ~0ull;
        const int wave = t >> 6, lane = t & 63;
        const int row = base + wave * 2 + (lane >> 5);
        const int l = lane & 31, b = l >> 3, j = l & 7;
        const float* a = x + (size_t)row * D_DIM + b * 128 + j;
        float r = __fmul_rn(a[0], a[0]);
#pragma unroll
        for (int i = 1; i < 16; ++i) {
            const float v = a[i * 8];
            r = __fadd_rn(r, __fmul_rn(v, v));
        }
        r = __fadd_rn(r, __shfl_xor(r, 1));
        r = __fadd_rn(r, __shfl_xor(r, 2));
        r = __fadd_rn(r, __shfl_xor(r, 4));
        r = __fadd_rn(r, __shfl_xor(r, 8));
        r = __fadd_rn(r, __shfl_xor(r, 16));
        if (l == 0) sn[row] = r;
    }
}

// non-pre path: standalone sn+init (prepass skipped)
__global__ __launch_bounds__(256)
void vq_sn(const float* __restrict__ x, float* __restrict__ sn,
           u64* __restrict__ keys, int* __restrict__ count) {
    const int t = threadIdx.x;
    const int base = blockIdx.x * 8;
    if (blockIdx.x == 0 && t == 0) *count = 0;
    if (t < 8) keys[base + t] = ~0ull;
    const int wave = t >> 6, lane = t & 63;
    const int row = base + wave * 2 + (lane >> 5);
    const int l = lane & 31, b = l >> 3, j = l & 7;
    const float* a = x + (size_t)row * D_DIM + b * 128 + j;
    float r = __fmul_rn(a[0], a[0]);
#pragma unroll
    for (int i = 1; i < 16; ++i) {
        const float v = a[i * 8];
        r = __fadd_rn(r, __fmul_rn(v, v));
    }
    r = __fadd_rn(r, __shfl_xor(r, 1));
    r = __fadd_rn(r, __shfl_xor(r, 2));
    r = __fadd_rn(r, __shfl_xor(r, 4));
    r = __fadd_rn(r, __shfl_xor(r, 8));
    r = __fadd_rn(r, __shfl_xor(r, 16));
    if (l == 0) sn[row] = r;
}

// ---------------------------------------------------------------------------
// K1: screening GEMM. 128 rows x 256 codes, 4 waves of 64x128, single
// bf16-hi MFMA, XOR-swizzled LDS. PRE path adds a one-slab register
// prefetch: global loads for dc+1 issue right after the ds_writes of dc,
// hiding load latency behind barrier + frag reads + 32 MFMAs.
// ---------------------------------------------------------------------------
template<bool PRE>
__global__ __launch_bounds__(256, 2)
void vq_screen2(const float* __restrict__ x, const float* __restrict__ cb,
                const ushort* __restrict__ xb, const ushort* __restrict__ cbb,
                float* __restrict__ g_dmax, uchar* __restrict__ g_cnt,
                uchar* __restrict__ g_cand) {
    __shared__ ushort Ash[128 * 32];
    __shared__ ushort Bsh[256 * 32];
    __shared__ unsigned vkey[128];
    __shared__ int ccnt[128];
    __shared__ uchar clist[128][CAP];

    const int t    = threadIdx.x;
    const int w    = t >> 6, lane = t & 63;
    const int fr   = lane & 15;
    const int quad = lane >> 4;
    const int wr   = (w & 1) * 64;
    const int wc   = (w >> 1) * 128;
    const int row0  = blockIdx.y * 128;
    const int kbase = blockIdx.x * 256;

    if (t < 128) { vkey[t] = 0u; ccnt[t] = 0; }

    const int r = t >> 1, h = t & 1;
    const int sA = (r >> 1) & 3;
    const int ca0 = (2 * h) ^ sA;
    ushort* awp0 = &Ash[r * 32 + ca0 * 8];
    ushort* awp1 = &Ash[r * 32 + (ca0 ^ 1) * 8];
    const int sB = (t >> 1) & 3;
    ushort* bwp0 = &Bsh[t * 32 + (0 ^ sB) * 8];
    ushort* bwp1 = &Bsh[t * 32 + (1 ^ sB) * 8];
    ushort* bwp2 = &Bsh[t * 32 + (2 ^ sB) * 8];
    ushort* bwp3 = &Bsh[t * 32 + (3 ^ sB) * 8];

    int aoff[4], boff[8];
#pragma unroll
    for (int i = 0; i < 4; ++i) {
        const int rw = wr + i * 16 + fr;
        aoff[i] = rw * 32 + ((quad ^ (rw >> 1)) & 3) * 8;
    }
#pragma unroll
    for (int j = 0; j < 8; ++j) {
        const int rw = wc + j * 16 + fr;
        boff[j] = rw * 32 + ((quad ^ (rw >> 1)) & 3) * 8;
    }

    f32x4 acc[4][8];
#pragma unroll
    for (int i = 0; i < 4; ++i)
#pragma unroll
        for (int j = 0; j < 8; ++j) acc[i][j] = (f32x4)0.0f;

    if (PRE) {
        const char* gA = (const char*)(xb  + (size_t)(row0 + r) * D_DIM + h * 16);
        const char* gB = (const char*)(cbb + (size_t)(kbase + t) * D_DIM);
        uint4 a0 = *(const uint4*)(gA);
        uint4 a1 = *(const uint4*)(gA + 16);
        uint4 b0 = *(const uint4*)(gB);
        uint4 b1 = *(const uint4*)(gB + 16);
        uint4 b2 = *(const uint4*)(gB + 32);
        uint4 b3 = *(const uint4*)(gB + 48);
        for (int dc = 0; dc < 16; ++dc) {
            __syncthreads();
            *(uint4*)awp0 = a0; *(uint4*)awp1 = a1;
            *(uint4*)bwp0 = b0; *(uint4*)bwp1 = b1;
            *(uint4*)bwp2 = b2; *(uint4*)bwp3 = b3;
            // prefetch next slab (last iter reloads slab 0 — harmless)
            const int dn = (dc + 1) & 15;
            a0 = *(const uint4*)(gA + dn * 64);
            a1 = *(const uint4*)(gA + dn * 64 + 16);
            b0 = *(const uint4*)(gB + dn * 64);
            b1 = *(const uint4*)(gB + dn * 64 + 16);
            b2 = *(const uint4*)(gB + dn * 64 + 32);
            b3 = *(const uint4*)(gB + dn * 64 + 48);
            __syncthreads();
            bf16x8 af[4], bfv[8];
#pragma unroll
            for (int i = 0; i < 4; ++i) af[i] = *(const bf16x8*)&Ash[aoff[i]];
#pragma unroll
            for (int j = 0; j < 8; ++j) bfv[j] = *(const bf16x8*)&Bsh[boff[j]];
#pragma unroll
            for (int i = 0; i < 4; ++i)
#pragma unroll
                for (int j = 0; j < 8; ++j)
                    acc[i][j] = __builtin_amdgcn_mfma_f32_16x16x32_bf16(af[i], bfv[j], acc[i][j], 0, 0, 0);
        }
    } else {
        const char* gA = (const char*)(x  + (size_t)(row0 + r) * D_DIM + h * 16);
        const char* gB = (const char*)(cb + (size_t)(kbase + t) * D_DIM);
        for (int dc = 0; dc < 16; ++dc) {
            const float4* fa = (const float4*)(gA + dc * 128);
            float4 f0 = fa[0], f1 = fa[1], f2 = fa[2], f3 = fa[3];
            uint4 a0 = make_uint4(pk_bf16(f0.x, f0.y), pk_bf16(f0.z, f0.w),
                                  pk_bf16(f1.x, f1.y), pk_bf16(f1.z, f1.w));
            uint4 a1 = make_uint4(pk_bf16(f2.x, f2.y), pk_bf16(f2.z, f2.w),
                                  pk_bf16(f3.x, f3.y), pk_bf16(f3.z, f3.w));
            const float4* fb = (const float4*)(gB + dc * 128);
            float4 g0 = fb[0], g1 = fb[1], g2 = fb[2], g3 = fb[3];
            float4 g4 = fb[4], g5 = fb[5], g6 = fb[6], g7 = fb[7];
            uint4 b0 = make_uint4(pk_bf16(g0.x, g0.y), pk_bf16(g0.z, g0.w),
                                  pk_bf16(g1.x, g1.y), pk_bf16(g1.z, g1.w));
            uint4 b1 = make_uint4(pk_bf16(g2.x, g2.y), pk_bf16(g2.z, g2.w),
                                  pk_bf16(g3.x, g3.y), pk_bf16(g3.z, g3.w));
            uint4 b2 = make_uint4(pk_bf16(g4.x, g4.y), pk_bf16(g4.z, g4.w),
                                  pk_bf16(g5.x, g5.y), pk_bf16(g5.z, g5.w));
            uint4 b3 = make_uint4(pk_bf16(g6.x, g6.y), pk_bf16(g6.z, g6.w),
                                  pk_bf16(g7.x, g7.y), pk_bf16(g7.z, g7.w));
            __syncthreads();
            *(uint4*)awp0 = a0; *(uint4*)awp1 = a1;
            *(uint4*)bwp0 = b0; *(uint4*)bwp1 = b1;
            *(uint4*)bwp2 = b2; *(uint4*)bwp3 = b3;
            __syncthreads();
            bf16x8 af[4], bfv[8];
#pragma unroll
            for (int i = 0; i < 4; ++i) af[i] = *(const bf16x8*)&Ash[aoff[i]];
#pragma unroll
            for (int j = 0; j < 8; ++j) bfv[j] = *(const bf16x8*)&Bsh[boff[j]];
#pragma unroll
            for (int i = 0; i < 4; ++i)
#pragma unroll
                for (int j = 0; j < 8; ++j)
                    acc[i][j] = __builtin_amdgcn_mfma_f32_16x16x32_bf16(af[i], bfv[j], acc[i][j], 0, 0, 0);
        }
    }

    __syncthreads();
#pragma unroll
    for (int i = 0; i < 4; ++i)
#pragma unroll
        for (int rg = 0; rg < 4; ++rg) {
            float m = acc[i][0][rg];
#pragma unroll
            for (int j = 1; j < 8; ++j) m = fmaxf(m, acc[i][j][rg]);
            m = fmaxf(m, __shfl_xor(m, 1));
            m = fmaxf(m, __shfl_xor(m, 2));
            m = fmaxf(m, __shfl_xor(m, 4));
            m = fmaxf(m, __shfl_xor(m, 8));
            if (fr == 0) atomicMax(&vkey[wr + i * 16 + quad * 4 + rg], fkey(m));
        }
    __syncthreads();
#pragma unroll
    for (int i = 0; i < 4; ++i)
#pragma unroll
        for (int rg = 0; rg < 4; ++rg) {
            const int row = wr + i * 16 + quad * 4 + rg;
            const float thr = finv(vkey[row]) - T2;
#pragma unroll
            for (int j = 0; j < 8; ++j) {
                if (acc[i][j][rg] >= thr) {
                    int p = atomicAdd(&ccnt[row], 1);
                    if (p < CAP) clist[row][p] = (uchar)(wc + j * 16 + fr);
                }
            }
        }
    __syncthreads();
    if (t < 128) {
        const size_t o = (size_t)(row0 + t) * NSPLIT + blockIdx.x;
        g_dmax[o] = finv(vkey[t]);
        int c = ccnt[t];
        g_cnt[o] = (uchar)(c > 255 ? 255 : c);
        ((uint2*)g_cand)[o] = *(const uint2*)clist[t];
    }
}

// ---------------------------------------------------------------------------
// K2: shortlist build, wave-aggregated list allocation (1 atomic per wave).
// ---------------------------------------------------------------------------
__global__ __launch_bounds__(256)
void vq_build(const float* __restrict__ g_dmax, const uchar* __restrict__ g_cnt,
              const uchar* __restrict__ g_cand, int2* __restrict__ list,
              int* __restrict__ count, float* __restrict__ idx_f) {
    const int row = blockIdx.x * blockDim.x + threadIdx.x;
    const int lane = threadIdx.x & 63;
    const float* dm = g_dmax + (size_t)row * NSPLIT;
    float g = dm[0];
#pragma unroll
    for (int s = 1; s < NSPLIT; ++s) g = fmaxf(g, dm[s]);
    const float thr = g - T2;

    int tot = 0, first = -1;
    for (int s = 0; s < NSPLIT; ++s) {
        if (dm[s] < thr) continue;
        const size_t o = (size_t)row * NSPLIT + s;
        const int c = g_cnt[o];
        tot += (c > CAP) ? 256 : c;
        if (first < 0) first = s * 256 + g_cand[o * CAP];
    }
    idx_f[row] = (float)first;   // final for tot==1; replay overrides otherwise

    const int need = (tot > 1) ? tot : 0;
    // wave inclusive prefix-sum of need
    int scan = need;
#pragma unroll
    for (int d = 1; d < 64; d <<= 1) {
        const int v = __shfl_up(scan, d, 64);
        if (lane >= d) scan += v;
    }
    const int wtot = __shfl(scan, 63, 64);
    int base = 0;
    if (lane == 63 && wtot > 0) base = atomicAdd(count, wtot);
    base = __shfl(base, 63, 64);
    if (need == 0) return;
    int pos = base + scan - need;

    for (int s = 0; s < NSPLIT; ++s) {
        if (dm[s] < thr) continue;
        const size_t o = (size_t)row * NSPLIT + s;
        const int c = g_cnt[o];
        if (c > CAP) {
            for (int u = 0; u < 256; ++u, ++pos)
                if (pos < LIST_CAP) list[pos] = make_int2(row, s * 256 + u);
        } else {
            for (int u = 0; u < c; ++u, ++pos)
                if (pos < LIST_CAP) list[pos] = make_int2(row, s * 256 + g_cand[o * CAP + u]);
        }
    }
}

// bit-exact numpy fp32 (baseline SSE3) einsum — validated absmax=0 (r2,r4-r6)
__device__ __forceinline__ float np_einsum_dot(const float* __restrict__ a,
                                               const float* __restrict__ b) {
    float S0 = 0.f, S1 = 0.f, S2 = 0.f, S3 = 0.f;
    for (int i = 0; i < D_DIM; i += 16) {
        S0 = __fadd_rn(S0, __fmul_rn(a[i + 12], b[i + 12]));
        S1 = __fadd_rn(S1, __fmul_rn(a[i + 13], b[i + 13]));
        S2 = __fadd_rn(S2, __fmul_rn(a[i + 14], b[i + 14]));
        S3 = __fadd_rn(S3, __fmul_rn(a[i + 15], b[i + 15]));
        S0 = __fadd_rn(S0, __fmul_rn(a[i +  8], b[i +  8]));
        S1 = __fadd_rn(S1, __fmul_rn(a[i +  9], b[i +  9]));
        S2 = __fadd_rn(S2, __fmul_rn(a[i + 10], b[i + 10]));
        S3 = __fadd_rn(S3, __fmul_rn(a[i + 11], b[i + 11]));
        S0 = __fadd_rn(S0, __fmul_rn(a[i +  4], b[i +  4]));
        S1 = __fadd_rn(S1, __fmul_rn(a[i +  5], b[i +  5]));
        S2 = __fadd_rn(S2, __fmul_rn(a[i +  6], b[i +  6]));
        S3 = __fadd_rn(S3, __fmul_rn(a[i +  7], b[i +  7]));
        S0 = __fadd_rn(S0, __fmul_rn(a[i +  0], b[i +  0]));
        S1 = __fadd_rn(S1, __fmul_rn(a[i +  1], b[i +  1]));
        S2 = __fadd_rn(S2, __fmul_rn(a[i +  2], b[i +  2]));
        S3 = __fadd_rn(S3, __fmul_rn(a[i +  3], b[i +  3]));
    }
    return __fadd_rn(__fadd_rn(S0, S1), __fadd_rn(S2, S3));
}

// ---------------------------------------------------------------------------
// K3: lane-per-entry exact replay; atomicMin on packed (distKey<<32)|k.
// ---------------------------------------------------------------------------
__global__ __launch_bounds__(256)
void vq_replay(const float* __restrict__ x, const float* __restrict__ cb,
               const float* __restrict__ sn, const int2* __restrict__ list,
               const int* __restrict__ count, u64* __restrict__ keys) {
    const int i = blockIdx.x * blockDim.x + threadIdx.x;
    int n = *count; if (n > LIST_CAP) n = LIST_CAP;
    if (i >= n) return;
    const int2 e = list[i];
    const float* zr = x + (size_t)e.x * D_DIM;
    const float d = __fadd_rn(sn[e.x],
                              __fmul_rn(-2.0f, np_einsum_dot(zr, cb + (size_t)e.y * D_DIM)));
    const u64 key = ((u64)fkey(d) << 32) | (unsigned)e.y;
    atomicMin(&keys[e.x], key);
}

// ---------------------------------------------------------------------------
// K4: resolve + gather z_q (exact fp32 straight-through) + per-row loss.
// ---------------------------------------------------------------------------
__global__ void vq_gather_kernel(const float* __restrict__ x,
                                 const float* __restrict__ cb,
                                 const u64* __restrict__ keys,
                                 float* __restrict__ idx_f,
                                 float* __restrict__ zq_out,
                                 double* __restrict__ psum) {
    const int row = blockIdx.x;
    const int t   = threadIdx.x;   // 128
    const u64 ky = keys[row];
    const int k = (ky != ~0ull) ? (int)(ky & 0xffffffffu) : (int)idx_f[row];
    const float4 c  = ((const float4*)(cb + (size_t)k   * D_DIM))[t];
    const float4 xv = ((const float4*)(x  + (size_t)row * D_DIM))[t];
    float4 o;
    o.x = __fadd_rn(xv.x, __fsub_rn(c.x, xv.x));
    o.y = __fadd_rn(xv.y, __fsub_rn(c.y, xv.y));
    o.z = __fadd_rn(xv.z, __fsub_rn(c.z, xv.z));
    o.w = __fadd_rn(xv.w, __fsub_rn(c.w, xv.w));
    ((float4*)(zq_out + (size_t)row * D_DIM))[t] = o;
    const double d0 = (double)c.x - (double)xv.x;
    const double d1 = (double)c.y - (double)xv.y;
    const double d2 = (double)c.z - (double)xv.z;
    const double d3 = (double)c.w - (double)xv.w;
    double s = d0 * d0 + d1 * d1 + d2 * d2 + d3 * d3;
#pragma unroll
    for (int off = 32; off > 0; off >>= 1) s += __shfl_xor(s, off, 64);
    __shared__ double red[2];
    if ((t & 63) == 0) red[t >> 6] = s;
    __syncthreads();
    if (t == 0) {
        psum[row] = red[0] + red[1];
        idx_f[row] = (float)k;
    }
}

__global__ void vq_finalize2(const double* __restrict__ psum,
                             float* __restrict__ losses) {
    __shared__ double red[4];
    const int t = threadIdx.x;   // 256
    double s = 0.0;
    for (int i = t; i < N_ROWS; i += 256) s += psum[i];
#pragma unroll
    for (int off = 32; off > 0; off >>= 1) s += __shfl_xor(s, off, 64);
    if ((t & 63) == 0) red[t >> 6] = s;
    __syncthreads();
    if (t == 0) {
        const double tot = red[0] + red[1] + red[2] + red[3];
        const float l = (float)(tot / (double)((size_t)N_ROWS * D_DIM));
        losses[0] = l;
        losses[1] = l;
    }
}

extern "C" void kernel_launch(void* const* d_in, const int* in_sizes, int n_in,
                              void* d_out, int out_size, void* d_ws, size_t ws_size,
                              hipStream_t stream) {
    const float* x  = (const float*)d_in[0];   // [16384, 512]
    const float* cb = (const float*)d_in[1];   // [8192, 512]
    float* out    = (float*)d_out;
    float* zq     = out;
    float* losses = out + (size_t)N_ROWS * D_DIM;
    float* idx_f  = losses + 2;
    char* ws = (char*)d_ws;

    const bool pre = (ws_size >= ((size_t)32 << 20));
    char* base = pre ? (ws + ((size_t)24 << 20)) : ws;

    // base layout (~7.3 MB):
    float*  g_dmax = (float*)(base);                     // 2048 KB
    uchar*  g_cnt  = (uchar*)(base + (2048u << 10));     //  512 KB
    uchar*  g_cand = (uchar*)(base + (2560u << 10));     // 4096 KB
    float*  sn     = (float*)(base + (6656u << 10));     //   64 KB
    u64*    keys   = (u64*)  (base + (6720u << 10));     //  128 KB
    int2*   list   = (int2*) (base + (6848u << 10));     //  256 KB
    int*    count  = (int*)  (base + (7104u << 10));     //   64 KB slot
    double* psum   = (double*)(base + (7168u << 10));    //  128 KB

    if (pre) {
        ushort* xb  = (ushort*)ws;                               // 16 MB
        ushort* cbb = (ushort*)(ws + ((size_t)16 << 20));        // 8 MB
        hipLaunchKernelGGL(vq_prepass, dim3(8192), dim3(256), 0, stream,
                           x, cb, (unsigned*)xb, (unsigned*)cbb, sn, keys, count);
        hipLaunchKernelGGL((vq_screen2<true>), dim3(K_CODES / 256, N_ROWS / 128), dim3(256), 0, stream,
                           x, cb, xb, cbb, g_dmax, g_cnt, g_cand);
    } else {
        hipLaunchKernelGGL(vq_sn, dim3(N_ROWS / 8), dim3(256), 0, stream,
                           x, sn, keys, count);
        hipLaunchKernelGGL((vq_screen2<false>), dim3(K_CODES / 256, N_ROWS / 128), dim3(256), 0, stream,
                           x, cb, (const ushort*)nullptr, (const ushort*)nullptr,
                           g_dmax, g_cnt, g_cand);
    }
    hipLaunchKernelGGL(vq_build, dim3(N_ROWS / 256), dim3(256), 0, stream,
                       g_dmax, g_cnt, g_cand, list, count, idx_f);
    hipLaunchKernelGGL(vq_replay, dim3(LIST_CAP / 256), dim3(256), 0, stream,
                       x, cb, sn, list, count, keys);
    hipLaunchKernelGGL(vq_gather_kernel, dim3(N_ROWS), dim3(128), 0, stream,
                       x, cb, keys, idx_f, zq, psum);
    hipLaunchKernelGGL(vq_finalize2, dim3(1), dim3(256), 0, stream,
                       psum, losses);
}